// Round 12
// baseline (934.771 us; speedup 1.0000x reference)
//
#include <hip/hip_runtime.h>

// ---------------------------------------------------------------------------
// E89 ResidualStateCell.
// Precision: k,v,decay (feed the recurrence) via split-bf16 (hi+lo) MFMA ->
// fp32; q,Sq,Wout (read-out only) via fp16 MFMA. Scan fp32 with fast tanh.
// R11 lesson: scan pinned at ~453 cyc/step = chain-latency-bound with only
// 1.75 waves/SIMD (barrier-aligned stalls). This round: 1024-thread scan
// blocks, 1 element/lane, 2 columns/wave (split-half mapping) -> 3.5
// waves/SIMD; 32-lane reduce = dpp_sum16 + v_permlane32_swap (all-VALU).
// Layout: k,v,q transposed [B][H][T][NS], decay [B][H][T].
// Memory: ws ~165 MB. q fp16 + decay live in d_out head (dead before the
// final out-GEMM overwrites it). x-fp16 aliases vf head; Sq aliases xh/xl.
// ---------------------------------------------------------------------------

typedef __attribute__((ext_vector_type(8))) __bf16 bf16x8;
typedef __attribute__((ext_vector_type(8))) _Float16 f16x8;
typedef __attribute__((ext_vector_type(4))) float f32x4;
typedef __attribute__((ext_vector_type(2))) float f32x2;
typedef __attribute__((ext_vector_type(2))) unsigned int u32x2v;

#define T_LEN 2048
#define BB 4
#define HH 56
#define NS 32
#define DIM 1024
#define KD 1792            // H*NS
#define MROWS 8192         // T_LEN*BB
#define CH 16              // scan chunk (steps)
#define NCHUNK (T_LEN / CH)

#define VMCNT(N) asm volatile("s_waitcnt vmcnt(" #N ")" ::: "memory")
#define LGKM(N)  asm volatile("s_waitcnt lgkmcnt(" #N ")" ::: "memory")
#define SB       __builtin_amdgcn_sched_barrier(0)

__device__ __forceinline__ float bf2f(unsigned short u) {
    return __uint_as_float(((unsigned int)u) << 16);
}
__device__ __forceinline__ unsigned short f2bf(float f) {
    unsigned int u = __float_as_uint(f);
    u += 0x7fffu + ((u >> 16) & 1u);          // round-to-nearest-even
    return (unsigned short)(u >> 16);
}
__device__ __forceinline__ unsigned short f2h(float f) {
    union { _Float16 h; unsigned short u; } cv;
    cv.h = (_Float16)f;                       // RNE
    return cv.u;
}
__device__ __forceinline__ float h2f(unsigned short u) {
    union { unsigned short u; _Float16 h; } cv;
    cv.u = u;
    return (float)cv.h;
}

// tanh via v_exp_f32 (2^x): tanh(x) = 1 - 2/(1+2^(2*log2e*x))
__device__ __forceinline__ float tanh_fast(float x) {
    float e = __builtin_amdgcn_exp2f(x * 2.885390081777927f);
    float r = __builtin_amdgcn_rcpf(e + 1.0f);
    return fmaf(-2.0f, r, 1.0f);
}

// Sum across each aligned group of 16 lanes, pure-VALU DPP butterfly.
__device__ __forceinline__ float dpp_sum16(float x) {
    int t;
    t = __builtin_amdgcn_update_dpp(0, __float_as_int(x), 0xB1, 0xf, 0xf, true);
    x += __int_as_float(t);
    t = __builtin_amdgcn_update_dpp(0, __float_as_int(x), 0x4E, 0xf, 0xf, true);
    x += __int_as_float(t);
    t = __builtin_amdgcn_update_dpp(0, __float_as_int(x), 0x141, 0xf, 0xf, true);
    x += __int_as_float(t);
    t = __builtin_amdgcn_update_dpp(0, __float_as_int(x), 0x140, 0xf, 0xf, true);
    x += __int_as_float(t);
    return x;
}

// After dpp_sum16, lane i holds its 16-row sum. permlane32_swap exchanges
// low/high wave halves; pr[0]+pr[1] = (this half's sum) + (other half's sum)
// in every lane -> full 32-element column sum (column = 16 low + 16 high).
__device__ __forceinline__ float swap_sum32(float x) {
    u32x2v pr = __builtin_amdgcn_permlane32_swap(
        __float_as_uint(x), __float_as_uint(x), false, false);
    return __uint_as_float(pr[0]) + __uint_as_float(pr[1]);
}

__device__ __forceinline__ void gload_lds16(const void* g, void* l) {
    __builtin_amdgcn_global_load_lds(
        (const __attribute__((address_space(1))) unsigned int*)g,
        (__attribute__((address_space(3))) unsigned int*)l, 16, 0, 0);
}
__device__ __forceinline__ void gload_lds4(const void* g, void* l) {
    __builtin_amdgcn_global_load_lds(
        (const __attribute__((address_space(1))) unsigned int*)g,
        (__attribute__((address_space(3))) unsigned int*)l, 4, 0, 0);
}

// LDS byte offset of a generic pointer to __shared__ memory.
__device__ __forceinline__ unsigned lds_off(const void* p) {
    return (unsigned)(unsigned long long)
        (const __attribute__((address_space(3))) char*)p;
}

// Inline-asm LDS reads (opaque to the compiler: cannot be sunk/reordered).
template <int OFF>
__device__ __forceinline__ f32x4 dsr128(unsigned a) {
    f32x4 r;
    asm volatile("ds_read_b128 %0, %1 offset:%2" : "=v"(r) : "v"(a), "n"(OFF));
    return r;
}
template <int OFF>
__device__ __forceinline__ unsigned dsr16(unsigned a) {
    unsigned r;
    asm volatile("ds_read_u16 %0, %1 offset:%2" : "=v"(r) : "v"(a), "n"(OFF));
    return r;
}
template <int OFF>
__device__ __forceinline__ float dsr32f(unsigned a) {
    float r;
    asm volatile("ds_read_b32 %0, %1 offset:%2" : "=v"(r) : "v"(a), "n"(OFF));
    return r;
}

// ---------------------------------------------------------------------------
// f32 -> (bf16 hi, bf16 lo, fp16) triple cast for x, 8 elements / thread
// ---------------------------------------------------------------------------
__global__ void cast_split3_kernel(const float* __restrict__ in,
                                   unsigned short* __restrict__ hi,
                                   unsigned short* __restrict__ lo,
                                   unsigned short* __restrict__ h16, int n8) {
    int i = blockIdx.x * blockDim.x + threadIdx.x;
    if (i >= n8) return;
    const float4* p = (const float4*)in + (size_t)i * 2;
    float4 a = p[0], b = p[1];
    float xs[8] = {a.x, a.y, a.z, a.w, b.x, b.y, b.z, b.w};
    unsigned int ho[4], lv[4], hv[4];
#pragma unroll
    for (int c = 0; c < 4; ++c) {
        unsigned short h0 = f2bf(xs[2 * c]);
        unsigned short h1 = f2bf(xs[2 * c + 1]);
        unsigned short l0 = f2bf(xs[2 * c] - bf2f(h0));
        unsigned short l1 = f2bf(xs[2 * c + 1] - bf2f(h1));
        ho[c] = (unsigned int)h0 | ((unsigned int)h1 << 16);
        lv[c] = (unsigned int)l0 | ((unsigned int)l1 << 16);
        hv[c] = (unsigned int)f2h(xs[2 * c]) | ((unsigned int)f2h(xs[2 * c + 1]) << 16);
    }
    ((uint4*)hi)[i]  = (uint4){ho[0], ho[1], ho[2], ho[3]};
    ((uint4*)lo)[i]  = (uint4){lv[0], lv[1], lv[2], lv[3]};
    ((uint4*)h16)[i] = (uint4){hv[0], hv[1], hv[2], hv[3]};
}

// ---------------------------------------------------------------------------
// f32 -> (bf16 hi, bf16 lo) split cast, 8 elements / thread
// ---------------------------------------------------------------------------
__global__ void cast_split_kernel(const float* __restrict__ in,
                                  unsigned short* __restrict__ hi,
                                  unsigned short* __restrict__ lo, int n8) {
    int i = blockIdx.x * blockDim.x + threadIdx.x;
    if (i >= n8) return;
    const float4* p = (const float4*)in + (size_t)i * 2;
    float4 a = p[0], b = p[1];
    float xs[8] = {a.x, a.y, a.z, a.w, b.x, b.y, b.z, b.w};
    unsigned int ho[4], lv[4];
#pragma unroll
    for (int c = 0; c < 4; ++c) {
        unsigned short h0 = f2bf(xs[2 * c]);
        unsigned short h1 = f2bf(xs[2 * c + 1]);
        unsigned short l0 = f2bf(xs[2 * c] - bf2f(h0));
        unsigned short l1 = f2bf(xs[2 * c + 1] - bf2f(h1));
        ho[c] = (unsigned int)h0 | ((unsigned int)h1 << 16);
        lv[c] = (unsigned int)l0 | ((unsigned int)l1 << 16);
    }
    ((uint4*)hi)[i] = (uint4){ho[0], ho[1], ho[2], ho[3]};
    ((uint4*)lo)[i] = (uint4){lv[0], lv[1], lv[2], lv[3]};
}

// ---------------------------------------------------------------------------
// f32 -> fp16 cast, 8 elements / thread
// ---------------------------------------------------------------------------
__global__ void cast_half_kernel(const float* __restrict__ in,
                                 unsigned short* __restrict__ out, int n8) {
    int i = blockIdx.x * blockDim.x + threadIdx.x;
    if (i >= n8) return;
    const float4* p = (const float4*)in + (size_t)i * 2;
    float4 a = p[0], b = p[1];
    uint4 o;
    o.x = (unsigned int)f2h(a.x) | ((unsigned int)f2h(a.y) << 16);
    o.y = (unsigned int)f2h(a.z) | ((unsigned int)f2h(a.w) << 16);
    o.z = (unsigned int)f2h(b.x) | ((unsigned int)f2h(b.y) << 16);
    o.w = (unsigned int)f2h(b.z) | ((unsigned int)f2h(b.w) << 16);
    ((uint4*)out)[i] = o;
}

// ---------------------------------------------------------------------------
// Split MFMA GEMM core: Y[m,n] = sum_k A[m,k]*B[n,k], A=Ah+Al, B=Bh+Bl.
// 128x128 tile, BK=32, 256 threads = 4 waves (2x2), 16x16x32 bf16 MFMA x3.
// ---------------------------------------------------------------------------
__device__ __forceinline__ void gemm_split(
    const unsigned short* __restrict__ Ah, const unsigned short* __restrict__ Al,
    const unsigned short* __restrict__ Bh, const unsigned short* __restrict__ Bl,
    int m0, int n0, int K, int bmax,
    unsigned short* AsH, unsigned short* AsL,
    unsigned short* BsH, unsigned short* BsL,
    f32x4 (&acc)[4][4]) {
    const int tid  = threadIdx.x;
    const int lane = tid & 63;
    const int wave = tid >> 6;
    const int wm = wave >> 1, wn = wave & 1;
    const int lr = lane & 15, lkb = lane >> 4;

#pragma unroll
    for (int fr = 0; fr < 4; ++fr)
#pragma unroll
        for (int fc = 0; fc < 4; ++fc) acc[fr][fc] = (f32x4){0.f, 0.f, 0.f, 0.f};

    auto stage = [&](int kt) {
#pragma unroll
        for (int c = 0; c < 2; ++c) {
            int i = c * 256 + tid;
            int r = i >> 2, kk = (i & 3) << 3;
            size_t ao = (size_t)(m0 + r) * K + kt + kk;
            int br = n0 + r; if (br > bmax) br = bmax;
            size_t bo = (size_t)br * K + kt + kk;
            gload_lds16(Ah + ao, AsH + i * 8);
            gload_lds16(Al + ao, AsL + i * 8);
            gload_lds16(Bh + bo, BsH + i * 8);
            gload_lds16(Bl + bo, BsL + i * 8);
        }
    };

    stage(0);
    const int nk = K >> 5;
    for (int t = 0; t < nk; ++t) {
        __syncthreads();                       // drains vmcnt -> LDS tiles ready
        bf16x8 ah[4], al[4], bh[4], bl[4];
#pragma unroll
        for (int f = 0; f < 4; ++f) {
            int ai = (wm * 64 + f * 16 + lr) * 32 + lkb * 8;
            int bi = (wn * 64 + f * 16 + lr) * 32 + lkb * 8;
            ah[f] = *(const bf16x8*)(AsH + ai);
            al[f] = *(const bf16x8*)(AsL + ai);
            bh[f] = *(const bf16x8*)(BsH + bi);
            bl[f] = *(const bf16x8*)(BsL + bi);
        }
#pragma unroll
        for (int fr = 0; fr < 4; ++fr)
#pragma unroll
            for (int fc = 0; fc < 4; ++fc) {
                acc[fr][fc] = __builtin_amdgcn_mfma_f32_16x16x32_bf16(
                    ah[fr], bh[fc], acc[fr][fc], 0, 0, 0);
                acc[fr][fc] = __builtin_amdgcn_mfma_f32_16x16x32_bf16(
                    ah[fr], bl[fc], acc[fr][fc], 0, 0, 0);
                acc[fr][fc] = __builtin_amdgcn_mfma_f32_16x16x32_bf16(
                    al[fr], bh[fc], acc[fr][fc], 0, 0, 0);
            }
        __syncthreads();                       // all waves done reading LDS
        if (t + 1 < nk) stage((t + 1) << 5);
    }
}

// ---------------------------------------------------------------------------
// Split projection (k or v) + optional decay tile.  Row m = t*BB + b.
// Tiles 0..13: silu (+ fused l2norm if knorm) -> fp32 dstF at [B][H][T][NS].
// Tile 14 (k launch only, grid.x=15): decay -> fp32 decayb at [B][H][T].
// ---------------------------------------------------------------------------
__global__ __launch_bounds__(256) void proj_split_kernel(
    const unsigned short* __restrict__ xh, const unsigned short* __restrict__ xl,
    const unsigned short* __restrict__ Wh, const unsigned short* __restrict__ Wl,
    const unsigned short* __restrict__ Wah, const unsigned short* __restrict__ Wal,
    const float* __restrict__ A_log, const float* __restrict__ dt_bias,
    float* __restrict__ dstF, float* __restrict__ decayb, int knorm) {
    __shared__ __align__(16) unsigned short AsH[128 * 32];
    __shared__ __align__(16) unsigned short AsL[128 * 32];
    __shared__ __align__(16) unsigned short BsH[128 * 32];
    __shared__ __align__(16) unsigned short BsL[128 * 32];

    const int tile = blockIdx.x;
    const bool isdecay = (tile == 14);
    int m0 = blockIdx.y * 128;
    int n0 = isdecay ? 0 : tile * 128;
    int bmax = isdecay ? (HH - 1) : (KD - 1);
    const unsigned short* Bh = isdecay ? Wah : Wh;
    const unsigned short* Bl = isdecay ? Wal : Wl;

    f32x4 acc[4][4];
    gemm_split(xh, xl, Bh, Bl, m0, n0, DIM, bmax, AsH, AsL, BsH, BsL, acc);

    const int lane = threadIdx.x & 63, wave = threadIdx.x >> 6;
    const int wm = wave >> 1, wn = wave & 1, lr = lane & 15, lkb = lane >> 4;

    if (isdecay) {
#pragma unroll
        for (int fr = 0; fr < 4; ++fr)
#pragma unroll
            for (int fc = 0; fc < 4; ++fc)
#pragma unroll
                for (int v = 0; v < 4; ++v) {
                    int m = m0 + wm * 64 + fr * 16 + lkb * 4 + v;
                    int n = n0 + wn * 64 + fc * 16 + lr;
                    int t = m >> 2, b = m & 3;
                    if (n < HH) {
                        float z = acc[fr][fc][v] + dt_bias[n];
                        float sp = (z > 20.f) ? z : log1pf(__expf(z));
                        decayb[((size_t)(b * HH + n)) * T_LEN + t] =
                            __expf(-__expf(A_log[n]) * sp);
                    }
                }
        return;
    }

    if (knorm) {
        // silu + fused l2norm over each head's 32 columns.
#pragma unroll
        for (int fr = 0; fr < 4; ++fr)
#pragma unroll
            for (int hc = 0; hc < 2; ++hc)
#pragma unroll
                for (int v = 0; v < 4; ++v) {
                    float yA = acc[fr][2 * hc][v];
                    float yB = acc[fr][2 * hc + 1][v];
                    float sA = yA / (1.f + __expf(-yA));
                    float sB = yB / (1.f + __expf(-yB));
                    float ss = fmaf(sA, sA, sB * sB);
                    ss = dpp_sum16(ss);            // sum over the head's 32 cols
                    float sc = 1.f / fmaxf(sqrtf(ss), 1e-12f);
                    int m = m0 + wm * 64 + fr * 16 + lkb * 4 + v;
                    int t = m >> 2, b = m & 3;
                    int h = ((n0 + wn * 64) >> 5) + hc;
                    size_t ro = (((size_t)(b * HH + h)) * T_LEN + t) * NS;
                    dstF[ro + lr]      = sA * sc;
                    dstF[ro + lr + 16] = sB * sc;
                }
    } else {
#pragma unroll
        for (int fr = 0; fr < 4; ++fr)
#pragma unroll
            for (int fc = 0; fc < 4; ++fc)
#pragma unroll
                for (int v = 0; v < 4; ++v) {
                    int m = m0 + wm * 64 + fr * 16 + lkb * 4 + v;
                    int n = n0 + wn * 64 + fc * 16 + lr;
                    int t = m >> 2, b = m & 3;
                    int h = n >> 5, i = n & 31;
                    float y = acc[fr][fc][v];
                    float s = y / (1.f + __expf(-y));
                    dstF[(((size_t)(b * HH + h)) * T_LEN + t) * NS + i] = s;
                }
    }
}

// ---------------------------------------------------------------------------
// q projection, single fp16 MFMA (q is read-out-only): q = l2norm(silu(x@Wq^T)),
// fp16 store at [B][H][T][NS].
// ---------------------------------------------------------------------------
__global__ __launch_bounds__(256) void q_gemm_f16_kernel(
    const unsigned short* __restrict__ xf, const unsigned short* __restrict__ Wqf,
    unsigned short* __restrict__ dstH) {
    __shared__ __align__(16) unsigned short As[128 * 32];
    __shared__ __align__(16) unsigned short Bs[128 * 32];
    int m0 = blockIdx.y * 128, n0 = blockIdx.x * 128;

    const int tid  = threadIdx.x;
    const int lane = tid & 63;
    const int wave = tid >> 6;
    const int wm = wave >> 1, wn = wave & 1;
    const int lr = lane & 15, lkb = lane >> 4;

    f32x4 acc[4][4];
#pragma unroll
    for (int fr = 0; fr < 4; ++fr)
#pragma unroll
        for (int fc = 0; fc < 4; ++fc) acc[fr][fc] = (f32x4){0.f, 0.f, 0.f, 0.f};

    auto stage = [&](int kt) {
#pragma unroll
        for (int c = 0; c < 2; ++c) {
            int i = c * 256 + tid;
            int r = i >> 2, kk = (i & 3) << 3;
            gload_lds16(xf + (size_t)(m0 + r) * DIM + kt + kk, As + i * 8);
            gload_lds16(Wqf + (size_t)(n0 + r) * DIM + kt + kk, Bs + i * 8);
        }
    };

    stage(0);
    const int nk = DIM >> 5;
    for (int t = 0; t < nk; ++t) {
        __syncthreads();
        f16x8 af[4], bf[4];
#pragma unroll
        for (int f = 0; f < 4; ++f) {
            af[f] = *(const f16x8*)(As + (wm * 64 + f * 16 + lr) * 32 + lkb * 8);
            bf[f] = *(const f16x8*)(Bs + (wn * 64 + f * 16 + lr) * 32 + lkb * 8);
        }
#pragma unroll
        for (int fr = 0; fr < 4; ++fr)
#pragma unroll
            for (int fc = 0; fc < 4; ++fc)
                acc[fr][fc] = __builtin_amdgcn_mfma_f32_16x16x32_f16(
                    af[fr], bf[fc], acc[fr][fc], 0, 0, 0);
        __syncthreads();
        if (t + 1 < nk) stage((t + 1) << 5);
    }

#pragma unroll
    for (int fr = 0; fr < 4; ++fr)
#pragma unroll
        for (int hc = 0; hc < 2; ++hc)
#pragma unroll
            for (int v = 0; v < 4; ++v) {
                float yA = acc[fr][2 * hc][v];
                float yB = acc[fr][2 * hc + 1][v];
                float sA = yA / (1.f + __expf(-yA));
                float sB = yB / (1.f + __expf(-yB));
                float ss = fmaf(sA, sA, sB * sB);
                ss = dpp_sum16(ss);
                float sc = 1.f / fmaxf(sqrtf(ss), 1e-12f);
                int m = m0 + wm * 64 + fr * 16 + lkb * 4 + v;
                int t = m >> 2, b = m & 3;
                int h = ((n0 + wn * 64) >> 5) + hc;
                size_t ro = (((size_t)(b * HH + h)) * T_LEN + t) * NS;
                dstH[ro + lr]      = f2h(sA * sc);
                dstH[ro + lr + 16] = f2h(sB * sc);
            }
}

// ---------------------------------------------------------------------------
// Output GEMM (fp16): out = Sq @ Wout^T, f32 store.
// ---------------------------------------------------------------------------
__global__ __launch_bounds__(256) void out_gemm_kernel(
    const unsigned short* __restrict__ Sq, const unsigned short* __restrict__ Wo,
    float* __restrict__ out) {
    __shared__ __align__(16) unsigned short As[128 * 32];
    __shared__ __align__(16) unsigned short Bs[128 * 32];
    int m0 = blockIdx.y * 128, n0 = blockIdx.x * 128;

    const int tid  = threadIdx.x;
    const int lane = tid & 63;
    const int wave = tid >> 6;
    const int wm = wave >> 1, wn = wave & 1;
    const int lr = lane & 15, lkb = lane >> 4;

    f32x4 acc[4][4];
#pragma unroll
    for (int fr = 0; fr < 4; ++fr)
#pragma unroll
        for (int fc = 0; fc < 4; ++fc) acc[fr][fc] = (f32x4){0.f, 0.f, 0.f, 0.f};

    auto stage = [&](int kt) {
#pragma unroll
        for (int c = 0; c < 2; ++c) {
            int i = c * 256 + tid;
            int r = i >> 2, kk = (i & 3) << 3;
            gload_lds16(Sq + (size_t)(m0 + r) * KD + kt + kk, As + i * 8);
            gload_lds16(Wo + (size_t)(n0 + r) * KD + kt + kk, Bs + i * 8);
        }
    };

    stage(0);
    const int nk = KD >> 5;
    for (int t = 0; t < nk; ++t) {
        __syncthreads();
        f16x8 af[4], bf[4];
#pragma unroll
        for (int f = 0; f < 4; ++f) {
            af[f] = *(const f16x8*)(As + (wm * 64 + f * 16 + lr) * 32 + lkb * 8);
            bf[f] = *(const f16x8*)(Bs + (wn * 64 + f * 16 + lr) * 32 + lkb * 8);
        }
#pragma unroll
        for (int fr = 0; fr < 4; ++fr)
#pragma unroll
            for (int fc = 0; fc < 4; ++fc)
                acc[fr][fc] = __builtin_amdgcn_mfma_f32_16x16x32_f16(
                    af[fr], bf[fc], acc[fr][fc], 0, 0, 0);
        __syncthreads();
        if (t + 1 < nk) stage((t + 1) << 5);
    }

#pragma unroll
    for (int fr = 0; fr < 4; ++fr)
#pragma unroll
        for (int fc = 0; fc < 4; ++fc)
#pragma unroll
            for (int v = 0; v < 4; ++v) {
                int m = m0 + wm * 64 + fr * 16 + lkb * 4 + v;
                int n = n0 + wn * 64 + fc * 16 + lr;
                out[(size_t)m * DIM + n] = acc[fr][fc][v];
            }
}

// ---------------------------------------------------------------------------
// Sequential scan: 1024 threads (16 waves) per (b,h); 1 state element/lane,
// 2 columns per wave (column c: 16 lanes low half + 16 lanes high half) ->
// 3584 waves = 3.5 waves/SIMD. Reduce = dpp_sum16 + permlane32_swap.
// LDS chunk ring (4-deep, staged 2 ahead, counted vmcnt) + in-chunk 4-step
// groups via inline-asm ds_read with counted lgkmcnt(13)
// (4xb32 k + 4xu16 q + 4xb32 v + 1xb128 d-broadcast = 13 DS ops/group).
// ---------------------------------------------------------------------------
__global__ __launch_bounds__(1024, 1) void scan_kernel(
    const float* __restrict__ kf, const unsigned short* __restrict__ qh,
    const float* __restrict__ vf, const float* __restrict__ decayb,
    const float* __restrict__ S0, unsigned short* __restrict__ Sq,
    float* __restrict__ Sout) {
    __shared__ __align__(16) float          kbuf[4][CH][NS];   // 8 KB
    __shared__ __align__(16) float          vbuf[4][CH][NS];   // 8 KB
    __shared__ __align__(16) unsigned short qbuf[4][CH][NS];   // 4 KB
    __shared__ __align__(16) float          dbuf[4][64];       // 1 KB

    const int bh = blockIdx.x;                 // 0..223  (= b*HH + h)
    const int b = bh / HH, h = bh - b * HH;
    const int tid = threadIdx.x;               // 0..1023
    const int lane = tid & 63, wave = tid >> 6;
    const int col = (wave << 1) | ((lane >> 4) & 1);       // 0..31
    const int e   = (lane & 15) | ((lane >> 5) << 4);      // element 0..31

    const float* Sp = S0 + (size_t)bh * NS * NS;
    float s0 = Sp[(size_t)e * NS + col];

    const size_t base  = (size_t)bh * T_LEN * NS;
    const size_t dbase = (size_t)bh * T_LEN;
    const size_t cbcol = (size_t)h * NS;       // Sq column base

    // per-lane LDS base offsets (slot 0)
    const unsigned kb0 = lds_off(&kbuf[0][0][0]) + (unsigned)e * 4;
    const unsigned qb0 = lds_off(&qbuf[0][0][0]) + (unsigned)e * 2;
    const unsigned vb0 = lds_off(&vbuf[0][0][0]) + (unsigned)col * 4;
    const unsigned db0 = lds_off(&dbuf[0][0]);

    // Wave-specialized chunk staging: waves 0-5 each issue ONE vm op/stage.
    auto stage = [&](int c) {
        int s = c & 3;
        if (wave == 0) {
            gload_lds16(kf + base + (size_t)c * 512 + lane * 4,
                        &kbuf[s][0][0] + lane * 4);
        } else if (wave == 1) {
            gload_lds16(kf + base + (size_t)c * 512 + 256 + lane * 4,
                        &kbuf[s][8][0] + lane * 4);
        } else if (wave == 2) {
            gload_lds16(vf + base + (size_t)c * 512 + lane * 4,
                        &vbuf[s][0][0] + lane * 4);
        } else if (wave == 3) {
            gload_lds16(vf + base + (size_t)c * 512 + 256 + lane * 4,
                        &vbuf[s][8][0] + lane * 4);
        } else if (wave == 4) {
            gload_lds16(qh + base + (size_t)c * 512 + lane * 8,
                        &qbuf[s][0][0] + lane * 8);
        } else if (wave == 5) {
            gload_lds4(decayb + dbase + (size_t)c * CH + lane,
                       &dbuf[s][0] + lane);    // tail lanes: junk, unused
        }
    };

    stage(0);
    stage(1);
    VMCNT(0);
    __builtin_amdgcn_s_barrier();

    for (int c = 0; c < NCHUNK; ++c) {
        if (c + 2 < NCHUNK) stage(c + 2);
        // Staging waves: outstanding = stage(c+1) + stage(c+2) + 16 Sq stores
        // of chunk c-1 = 18; stage(c) is older -> VMCNT(18) drains it.
        if (wave < 6) { VMCNT(18); }
        __builtin_amdgcn_s_barrier();
        SB;

        const int s = c & 3;
        const unsigned kb = kb0 + (unsigned)s * (CH * NS * 4);
        const unsigned qb = qb0 + (unsigned)s * (CH * NS * 2);
        const unsigned vb = vb0 + (unsigned)s * (CH * NS * 4);
        const unsigned db = db0 + (unsigned)s * 256;

        float kA[4], kB[4]; unsigned qA[4], qB[4]; float vA[4], vB[4];
        f32x4 dA, dB;

#define LDG(KK, QQ, VV, DV, g)                                          \
        KK[0] = dsr32f<((g) * 4 + 0) * 128>(kb);                        \
        KK[1] = dsr32f<((g) * 4 + 1) * 128>(kb);                        \
        KK[2] = dsr32f<((g) * 4 + 2) * 128>(kb);                        \
        KK[3] = dsr32f<((g) * 4 + 3) * 128>(kb);                        \
        QQ[0] = dsr16<((g) * 4 + 0) * 64>(qb);                          \
        QQ[1] = dsr16<((g) * 4 + 1) * 64>(qb);                          \
        QQ[2] = dsr16<((g) * 4 + 2) * 64>(qb);                          \
        QQ[3] = dsr16<((g) * 4 + 3) * 64>(qb);                          \
        VV[0] = dsr32f<((g) * 4 + 0) * 128>(vb);                        \
        VV[1] = dsr32f<((g) * 4 + 1) * 128>(vb);                        \
        VV[2] = dsr32f<((g) * 4 + 2) * 128>(vb);                        \
        VV[3] = dsr32f<((g) * 4 + 3) * 128>(vb);                        \
        DV    = dsr128<(g) * 16>(db);          /* broadcast: 4 decays */

#define CMP(KK, QQ, VV, DV, g)                                          \
        {                                                               \
            _Pragma("unroll")                                           \
            for (int p = 0; p < 4; ++p) {                               \
                const int t = c * CH + (g) * 4 + p;                     \
                float k0 = KK[p];                                       \
                float q0 = h2f((unsigned short)QQ[p]);                  \
                float vj = VV[p];                                       \
                float d  = DV[p];                                       \
                float r = swap_sum32(dpp_sum16(k0 * s0));               \
                float delta = vj - r;                                   \
                float a0 = fmaf(d, s0, k0 * delta);                     \
                s0 += tanh_fast(a0);                                    \
                float o = swap_sum32(dpp_sum16(q0 * s0));               \
                if (e == 0) {                                           \
                    size_t ro = ((size_t)t * BB + b) * KD + cbcol;      \
                    Sq[ro + col] = f2h(o);                              \
                }                                                       \
            }                                                           \
        }

        // 4-step group pipeline: asm ds_reads can't be sunk; counted
        // lgkmcnt(13) = wait group done while next group's 13 stay in flight.
        LDG(kA, qA, vA, dA, 0);
        LDG(kB, qB, vB, dB, 1);
        LGKM(13); SB;                 // A ready (B's 13 still in flight)
        CMP(kA, qA, vA, dA, 0);
        LDG(kA, qA, vA, dA, 2);
        LGKM(13); SB;                 // B ready (A2 in flight)
        CMP(kB, qB, vB, dB, 1);
        LDG(kB, qB, vB, dB, 3);
        LGKM(13); SB;                 // A2 ready (B2 in flight)
        CMP(kA, qA, vA, dA, 2);
        LGKM(0); SB;                  // B2 ready
        CMP(kB, qB, vB, dB, 3);
#undef LDG
#undef CMP
    }

    float* so = Sout + (size_t)bh * NS * NS;
    so[(size_t)e * NS + col] = s0;
}

// ---------------------------------------------------------------------------
extern "C" void kernel_launch(void* const* d_in, const int* in_sizes, int n_in,
                              void* d_out, int out_size, void* d_ws, size_t ws_size,
                              hipStream_t stream) {
    const float* x       = (const float*)d_in[0];
    const float* S0      = (const float*)d_in[1];
    const float* Wq      = (const float*)d_in[2];
    const float* Wk      = (const float*)d_in[3];
    const float* Wv      = (const float*)d_in[4];
    const float* Wa      = (const float*)d_in[5];
    const float* A_log   = (const float*)d_in[6];
    const float* dt_bias = (const float*)d_in[7];
    const float* Wout    = (const float*)d_in[8];

    float* out  = (float*)d_out;
    float* Sout = out + (size_t)T_LEN * BB * DIM;

    // --- workspace layout (~165 MB peak) ---
    char* w = (char*)d_ws;
    auto alloc = [&](size_t bytes) {
        char* p = w; w += (bytes + 255) & ~(size_t)255; return p;
    };
    unsigned short* xh  = (unsigned short*)alloc((size_t)MROWS * DIM * 2);  // 16.8 MB
    unsigned short* xl  = (unsigned short*)alloc((size_t)MROWS * DIM * 2);  // 16.8 MB
    unsigned short* Wbh = (unsigned short*)alloc((size_t)KD * DIM * 2);     // 3.67 MB (reused)
    unsigned short* Wbl = (unsigned short*)alloc((size_t)KD * DIM * 2);     // 3.67 MB (reused)
    unsigned short* Wah = (unsigned short*)alloc((size_t)HH * DIM * 2);     // 0.11 MB
    unsigned short* Wal = (unsigned short*)alloc((size_t)HH * DIM * 2);     // 0.11 MB
    float* kf           = (float*)alloc((size_t)MROWS * KD * 4);            // 58.7 MB
    float* vf           = (float*)alloc((size_t)MROWS * KD * 4);            // 58.7 MB
    unsigned short* Woh = (unsigned short*)alloc((size_t)DIM * KD * 2);     // 3.67 MB
    // Aliases: Sq (fp16) over xh/xl (x dead after last proj GEMM);
    //          x-fp16 over vf head (dead once v-proj runs, after q-proj).
    unsigned short* Sq   = xh;
    unsigned short* xf16 = (unsigned short*)vf;

    // --- d_out head as scratch for q (fp16) + decay: dead before out GEMM ---
    unsigned short* qh  = (unsigned short*)d_out;                 // 29.36 MB
    float* decayb       = (float*)((char*)d_out + (size_t)MROWS * KD * 2); // 1.83 MB

    // 1) x -> bf16 hi/lo + fp16 (fp16 copy aliased in vf head)
    {
        int n8 = (int)((size_t)MROWS * DIM / 8);
        cast_split3_kernel<<<(n8 + 255) / 256, 256, 0, stream>>>(x, xh, xl, xf16, n8);
    }
    // 2) q projection (single fp16 MFMA, fused l2norm): Wq fp16 staged in Wbh
    {
        int n8 = (int)((size_t)KD * DIM / 8);
        cast_half_kernel<<<(n8 + 255) / 256, 256, 0, stream>>>(Wq, Wbh, n8);
        q_gemm_f16_kernel<<<dim3(14, 64), 256, 0, stream>>>(xf16, Wbh, qh);
    }
    // 3) k projection (fused l2norm) + decay (tile 14), split-bf16
    {
        int n8 = (int)((size_t)KD * DIM / 8);
        cast_split_kernel<<<(n8 + 255) / 256, 256, 0, stream>>>(Wk, Wbh, Wbl, n8);
        int n8a = (int)((size_t)HH * DIM / 8);
        cast_split_kernel<<<(n8a + 255) / 256, 256, 0, stream>>>(Wa, Wah, Wal, n8a);
        proj_split_kernel<<<dim3(15, 64), 256, 0, stream>>>(
            xh, xl, Wbh, Wbl, Wah, Wal, A_log, dt_bias, kf, decayb, 1);
    }
    // 4) v projection (no norm; overwrites xf16 alias -- dead after q-proj)
    {
        int n8 = (int)((size_t)KD * DIM / 8);
        cast_split_kernel<<<(n8 + 255) / 256, 256, 0, stream>>>(Wv, Wbh, Wbl, n8);
        proj_split_kernel<<<dim3(14, 64), 256, 0, stream>>>(
            xh, xl, Wbh, Wbl, Wah, Wal, A_log, dt_bias, vf, decayb, 0);
    }
    // 5) Wout -> fp16
    {
        int n8 = (int)((size_t)DIM * KD / 8);
        cast_half_kernel<<<(n8 + 255) / 256, 256, 0, stream>>>(Wout, Woh, n8);
    }
    // 6) scan (1024 threads per (b,h): 1 elem/lane, 2 cols/wave)
    scan_kernel<<<BB * HH, 1024, 0, stream>>>(kf, qh, vf, decayb, S0, Sq, Sout);
    // 7) output GEMM
    out_gemm_kernel<<<dim3(8, 64), 256, 0, stream>>>(Sq, Woh, out);
}

// Round 13
// 716.124 us; speedup vs baseline: 1.3053x; 1.3053x over previous
//
#include <hip/hip_runtime.h>

// ---------------------------------------------------------------------------
// E89 ResidualStateCell.
// Precision: k,v,decay (feed the recurrence) via split-bf16 (hi+lo) MFMA ->
// fp32; q,Sq,Wout (read-out only) via fp16 MFMA. Scan fp32 with fast tanh.
// R12 lesson: 1-elem/lane doubled total VALU work (issue-bound at 74%).
// Reverted to R11's 512-thread scan (16 lanes/col x 2 elems) + NEW: delayed-o
// dual reduction — o_t's DPP tree is reduced during step t+1, adjacent to
// r_{t+1}'s tree (independent -> interleaved), leaving ONE DPP tree on the
// serial chain instead of two.
// Layout: k,v,q transposed [B][H][T][NS], decay [B][H][T].
// Memory: ws ~165 MB. q fp16 + decay live in d_out head (dead before the
// final out-GEMM overwrites it). x-fp16 aliases vf head; Sq aliases xh/xl.
// ---------------------------------------------------------------------------

typedef __attribute__((ext_vector_type(8))) __bf16 bf16x8;
typedef __attribute__((ext_vector_type(8))) _Float16 f16x8;
typedef __attribute__((ext_vector_type(4))) float f32x4;
typedef __attribute__((ext_vector_type(2))) float f32x2;

#define T_LEN 2048
#define BB 4
#define HH 56
#define NS 32
#define DIM 1024
#define KD 1792            // H*NS
#define MROWS 8192         // T_LEN*BB
#define CH 16              // scan chunk (steps)
#define NCHUNK (T_LEN / CH)

#define VMCNT(N) asm volatile("s_waitcnt vmcnt(" #N ")" ::: "memory")
#define LGKM(N)  asm volatile("s_waitcnt lgkmcnt(" #N ")" ::: "memory")
#define SB       __builtin_amdgcn_sched_barrier(0)

__device__ __forceinline__ float bf2f(unsigned short u) {
    return __uint_as_float(((unsigned int)u) << 16);
}
__device__ __forceinline__ unsigned short f2bf(float f) {
    unsigned int u = __float_as_uint(f);
    u += 0x7fffu + ((u >> 16) & 1u);          // round-to-nearest-even
    return (unsigned short)(u >> 16);
}
__device__ __forceinline__ unsigned short f2h(float f) {
    union { _Float16 h; unsigned short u; } cv;
    cv.h = (_Float16)f;                       // RNE
    return cv.u;
}
__device__ __forceinline__ float h2f(unsigned short u) {
    union { unsigned short u; _Float16 h; } cv;
    cv.u = u;
    return (float)cv.h;
}

// tanh via v_exp_f32 (2^x): tanh(x) = 1 - 2/(1+2^(2*log2e*x))
__device__ __forceinline__ float tanh_fast(float x) {
    float e = __builtin_amdgcn_exp2f(x * 2.885390081777927f);
    float r = __builtin_amdgcn_rcpf(e + 1.0f);
    return fmaf(-2.0f, r, 1.0f);
}

// Sum across each aligned group of 16 lanes, pure-VALU DPP butterfly.
__device__ __forceinline__ float dpp_sum16(float x) {
    int t;
    t = __builtin_amdgcn_update_dpp(0, __float_as_int(x), 0xB1, 0xf, 0xf, true);
    x += __int_as_float(t);
    t = __builtin_amdgcn_update_dpp(0, __float_as_int(x), 0x4E, 0xf, 0xf, true);
    x += __int_as_float(t);
    t = __builtin_amdgcn_update_dpp(0, __float_as_int(x), 0x141, 0xf, 0xf, true);
    x += __int_as_float(t);
    t = __builtin_amdgcn_update_dpp(0, __float_as_int(x), 0x140, 0xf, 0xf, true);
    x += __int_as_float(t);
    return x;
}

// Dual 16-lane sum: two independent DPP trees, interleaved for ILP.
__device__ __forceinline__ f32x2 dpp_sum16x2(float a, float b) {
    int ta, tb;
    ta = __builtin_amdgcn_update_dpp(0, __float_as_int(a), 0xB1, 0xf, 0xf, true);
    tb = __builtin_amdgcn_update_dpp(0, __float_as_int(b), 0xB1, 0xf, 0xf, true);
    a += __int_as_float(ta); b += __int_as_float(tb);
    ta = __builtin_amdgcn_update_dpp(0, __float_as_int(a), 0x4E, 0xf, 0xf, true);
    tb = __builtin_amdgcn_update_dpp(0, __float_as_int(b), 0x4E, 0xf, 0xf, true);
    a += __int_as_float(ta); b += __int_as_float(tb);
    ta = __builtin_amdgcn_update_dpp(0, __float_as_int(a), 0x141, 0xf, 0xf, true);
    tb = __builtin_amdgcn_update_dpp(0, __float_as_int(b), 0x141, 0xf, 0xf, true);
    a += __int_as_float(ta); b += __int_as_float(tb);
    ta = __builtin_amdgcn_update_dpp(0, __float_as_int(a), 0x140, 0xf, 0xf, true);
    tb = __builtin_amdgcn_update_dpp(0, __float_as_int(b), 0x140, 0xf, 0xf, true);
    a += __int_as_float(ta); b += __int_as_float(tb);
    return (f32x2){a, b};
}

__device__ __forceinline__ void gload_lds16(const void* g, void* l) {
    __builtin_amdgcn_global_load_lds(
        (const __attribute__((address_space(1))) unsigned int*)g,
        (__attribute__((address_space(3))) unsigned int*)l, 16, 0, 0);
}
__device__ __forceinline__ void gload_lds4(const void* g, void* l) {
    __builtin_amdgcn_global_load_lds(
        (const __attribute__((address_space(1))) unsigned int*)g,
        (__attribute__((address_space(3))) unsigned int*)l, 4, 0, 0);
}

// LDS byte offset of a generic pointer to __shared__ memory.
__device__ __forceinline__ unsigned lds_off(const void* p) {
    return (unsigned)(unsigned long long)
        (const __attribute__((address_space(3))) char*)p;
}

// Inline-asm LDS reads (opaque to the compiler: cannot be sunk/reordered).
template <int OFF>
__device__ __forceinline__ f32x4 dsr128(unsigned a) {
    f32x4 r;
    asm volatile("ds_read_b128 %0, %1 offset:%2" : "=v"(r) : "v"(a), "n"(OFF));
    return r;
}
template <int OFF>
__device__ __forceinline__ f32x2 dsr64f(unsigned a) {
    f32x2 r;
    asm volatile("ds_read_b64 %0, %1 offset:%2" : "=v"(r) : "v"(a), "n"(OFF));
    return r;
}
template <int OFF>
__device__ __forceinline__ unsigned dsr32u(unsigned a) {
    unsigned r;
    asm volatile("ds_read_b32 %0, %1 offset:%2" : "=v"(r) : "v"(a), "n"(OFF));
    return r;
}
template <int OFF>
__device__ __forceinline__ float dsr32f(unsigned a) {
    float r;
    asm volatile("ds_read_b32 %0, %1 offset:%2" : "=v"(r) : "v"(a), "n"(OFF));
    return r;
}

// ---------------------------------------------------------------------------
// f32 -> (bf16 hi, bf16 lo, fp16) triple cast for x, 8 elements / thread
// ---------------------------------------------------------------------------
__global__ void cast_split3_kernel(const float* __restrict__ in,
                                   unsigned short* __restrict__ hi,
                                   unsigned short* __restrict__ lo,
                                   unsigned short* __restrict__ h16, int n8) {
    int i = blockIdx.x * blockDim.x + threadIdx.x;
    if (i >= n8) return;
    const float4* p = (const float4*)in + (size_t)i * 2;
    float4 a = p[0], b = p[1];
    float xs[8] = {a.x, a.y, a.z, a.w, b.x, b.y, b.z, b.w};
    unsigned int ho[4], lv[4], hv[4];
#pragma unroll
    for (int c = 0; c < 4; ++c) {
        unsigned short h0 = f2bf(xs[2 * c]);
        unsigned short h1 = f2bf(xs[2 * c + 1]);
        unsigned short l0 = f2bf(xs[2 * c] - bf2f(h0));
        unsigned short l1 = f2bf(xs[2 * c + 1] - bf2f(h1));
        ho[c] = (unsigned int)h0 | ((unsigned int)h1 << 16);
        lv[c] = (unsigned int)l0 | ((unsigned int)l1 << 16);
        hv[c] = (unsigned int)f2h(xs[2 * c]) | ((unsigned int)f2h(xs[2 * c + 1]) << 16);
    }
    ((uint4*)hi)[i]  = (uint4){ho[0], ho[1], ho[2], ho[3]};
    ((uint4*)lo)[i]  = (uint4){lv[0], lv[1], lv[2], lv[3]};
    ((uint4*)h16)[i] = (uint4){hv[0], hv[1], hv[2], hv[3]};
}

// ---------------------------------------------------------------------------
// f32 -> (bf16 hi, bf16 lo) split cast, 8 elements / thread
// ---------------------------------------------------------------------------
__global__ void cast_split_kernel(const float* __restrict__ in,
                                  unsigned short* __restrict__ hi,
                                  unsigned short* __restrict__ lo, int n8) {
    int i = blockIdx.x * blockDim.x + threadIdx.x;
    if (i >= n8) return;
    const float4* p = (const float4*)in + (size_t)i * 2;
    float4 a = p[0], b = p[1];
    float xs[8] = {a.x, a.y, a.z, a.w, b.x, b.y, b.z, b.w};
    unsigned int ho[4], lv[4];
#pragma unroll
    for (int c = 0; c < 4; ++c) {
        unsigned short h0 = f2bf(xs[2 * c]);
        unsigned short h1 = f2bf(xs[2 * c + 1]);
        unsigned short l0 = f2bf(xs[2 * c] - bf2f(h0));
        unsigned short l1 = f2bf(xs[2 * c + 1] - bf2f(h1));
        ho[c] = (unsigned int)h0 | ((unsigned int)h1 << 16);
        lv[c] = (unsigned int)l0 | ((unsigned int)l1 << 16);
    }
    ((uint4*)hi)[i] = (uint4){ho[0], ho[1], ho[2], ho[3]};
    ((uint4*)lo)[i] = (uint4){lv[0], lv[1], lv[2], lv[3]};
}

// ---------------------------------------------------------------------------
// f32 -> fp16 cast, 8 elements / thread
// ---------------------------------------------------------------------------
__global__ void cast_half_kernel(const float* __restrict__ in,
                                 unsigned short* __restrict__ out, int n8) {
    int i = blockIdx.x * blockDim.x + threadIdx.x;
    if (i >= n8) return;
    const float4* p = (const float4*)in + (size_t)i * 2;
    float4 a = p[0], b = p[1];
    uint4 o;
    o.x = (unsigned int)f2h(a.x) | ((unsigned int)f2h(a.y) << 16);
    o.y = (unsigned int)f2h(a.z) | ((unsigned int)f2h(a.w) << 16);
    o.z = (unsigned int)f2h(b.x) | ((unsigned int)f2h(b.y) << 16);
    o.w = (unsigned int)f2h(b.z) | ((unsigned int)f2h(b.w) << 16);
    ((uint4*)out)[i] = o;
}

// ---------------------------------------------------------------------------
// Split MFMA GEMM core: Y[m,n] = sum_k A[m,k]*B[n,k], A=Ah+Al, B=Bh+Bl.
// 128x128 tile, BK=32, 256 threads = 4 waves (2x2), 16x16x32 bf16 MFMA x3.
// ---------------------------------------------------------------------------
__device__ __forceinline__ void gemm_split(
    const unsigned short* __restrict__ Ah, const unsigned short* __restrict__ Al,
    const unsigned short* __restrict__ Bh, const unsigned short* __restrict__ Bl,
    int m0, int n0, int K, int bmax,
    unsigned short* AsH, unsigned short* AsL,
    unsigned short* BsH, unsigned short* BsL,
    f32x4 (&acc)[4][4]) {
    const int tid  = threadIdx.x;
    const int lane = tid & 63;
    const int wave = tid >> 6;
    const int wm = wave >> 1, wn = wave & 1;
    const int lr = lane & 15, lkb = lane >> 4;

#pragma unroll
    for (int fr = 0; fr < 4; ++fr)
#pragma unroll
        for (int fc = 0; fc < 4; ++fc) acc[fr][fc] = (f32x4){0.f, 0.f, 0.f, 0.f};

    auto stage = [&](int kt) {
#pragma unroll
        for (int c = 0; c < 2; ++c) {
            int i = c * 256 + tid;
            int r = i >> 2, kk = (i & 3) << 3;
            size_t ao = (size_t)(m0 + r) * K + kt + kk;
            int br = n0 + r; if (br > bmax) br = bmax;
            size_t bo = (size_t)br * K + kt + kk;
            gload_lds16(Ah + ao, AsH + i * 8);
            gload_lds16(Al + ao, AsL + i * 8);
            gload_lds16(Bh + bo, BsH + i * 8);
            gload_lds16(Bl + bo, BsL + i * 8);
        }
    };

    stage(0);
    const int nk = K >> 5;
    for (int t = 0; t < nk; ++t) {
        __syncthreads();                       // drains vmcnt -> LDS tiles ready
        bf16x8 ah[4], al[4], bh[4], bl[4];
#pragma unroll
        for (int f = 0; f < 4; ++f) {
            int ai = (wm * 64 + f * 16 + lr) * 32 + lkb * 8;
            int bi = (wn * 64 + f * 16 + lr) * 32 + lkb * 8;
            ah[f] = *(const bf16x8*)(AsH + ai);
            al[f] = *(const bf16x8*)(AsL + ai);
            bh[f] = *(const bf16x8*)(BsH + bi);
            bl[f] = *(const bf16x8*)(BsL + bi);
        }
#pragma unroll
        for (int fr = 0; fr < 4; ++fr)
#pragma unroll
            for (int fc = 0; fc < 4; ++fc) {
                acc[fr][fc] = __builtin_amdgcn_mfma_f32_16x16x32_bf16(
                    ah[fr], bh[fc], acc[fr][fc], 0, 0, 0);
                acc[fr][fc] = __builtin_amdgcn_mfma_f32_16x16x32_bf16(
                    ah[fr], bl[fc], acc[fr][fc], 0, 0, 0);
                acc[fr][fc] = __builtin_amdgcn_mfma_f32_16x16x32_bf16(
                    al[fr], bh[fc], acc[fr][fc], 0, 0, 0);
            }
        __syncthreads();                       // all waves done reading LDS
        if (t + 1 < nk) stage((t + 1) << 5);
    }
}

// ---------------------------------------------------------------------------
// Split projection (k or v) + optional decay tile.  Row m = t*BB + b.
// Tiles 0..13: silu (+ fused l2norm if knorm) -> fp32 dstF at [B][H][T][NS].
// Tile 14 (k launch only, grid.x=15): decay -> fp32 decayb at [B][H][T].
// ---------------------------------------------------------------------------
__global__ __launch_bounds__(256) void proj_split_kernel(
    const unsigned short* __restrict__ xh, const unsigned short* __restrict__ xl,
    const unsigned short* __restrict__ Wh, const unsigned short* __restrict__ Wl,
    const unsigned short* __restrict__ Wah, const unsigned short* __restrict__ Wal,
    const float* __restrict__ A_log, const float* __restrict__ dt_bias,
    float* __restrict__ dstF, float* __restrict__ decayb, int knorm) {
    __shared__ __align__(16) unsigned short AsH[128 * 32];
    __shared__ __align__(16) unsigned short AsL[128 * 32];
    __shared__ __align__(16) unsigned short BsH[128 * 32];
    __shared__ __align__(16) unsigned short BsL[128 * 32];

    const int tile = blockIdx.x;
    const bool isdecay = (tile == 14);
    int m0 = blockIdx.y * 128;
    int n0 = isdecay ? 0 : tile * 128;
    int bmax = isdecay ? (HH - 1) : (KD - 1);
    const unsigned short* Bh = isdecay ? Wah : Wh;
    const unsigned short* Bl = isdecay ? Wal : Wl;

    f32x4 acc[4][4];
    gemm_split(xh, xl, Bh, Bl, m0, n0, DIM, bmax, AsH, AsL, BsH, BsL, acc);

    const int lane = threadIdx.x & 63, wave = threadIdx.x >> 6;
    const int wm = wave >> 1, wn = wave & 1, lr = lane & 15, lkb = lane >> 4;

    if (isdecay) {
#pragma unroll
        for (int fr = 0; fr < 4; ++fr)
#pragma unroll
            for (int fc = 0; fc < 4; ++fc)
#pragma unroll
                for (int v = 0; v < 4; ++v) {
                    int m = m0 + wm * 64 + fr * 16 + lkb * 4 + v;
                    int n = n0 + wn * 64 + fc * 16 + lr;
                    int t = m >> 2, b = m & 3;
                    if (n < HH) {
                        float z = acc[fr][fc][v] + dt_bias[n];
                        float sp = (z > 20.f) ? z : log1pf(__expf(z));
                        decayb[((size_t)(b * HH + n)) * T_LEN + t] =
                            __expf(-__expf(A_log[n]) * sp);
                    }
                }
        return;
    }

    if (knorm) {
        // silu + fused l2norm over each head's 32 columns.
#pragma unroll
        for (int fr = 0; fr < 4; ++fr)
#pragma unroll
            for (int hc = 0; hc < 2; ++hc)
#pragma unroll
                for (int v = 0; v < 4; ++v) {
                    float yA = acc[fr][2 * hc][v];
                    float yB = acc[fr][2 * hc + 1][v];
                    float sA = yA / (1.f + __expf(-yA));
                    float sB = yB / (1.f + __expf(-yB));
                    float ss = fmaf(sA, sA, sB * sB);
                    ss = dpp_sum16(ss);            // sum over the head's 32 cols
                    float sc = 1.f / fmaxf(sqrtf(ss), 1e-12f);
                    int m = m0 + wm * 64 + fr * 16 + lkb * 4 + v;
                    int t = m >> 2, b = m & 3;
                    int h = ((n0 + wn * 64) >> 5) + hc;
                    size_t ro = (((size_t)(b * HH + h)) * T_LEN + t) * NS;
                    dstF[ro + lr]      = sA * sc;
                    dstF[ro + lr + 16] = sB * sc;
                }
    } else {
#pragma unroll
        for (int fr = 0; fr < 4; ++fr)
#pragma unroll
            for (int fc = 0; fc < 4; ++fc)
#pragma unroll
                for (int v = 0; v < 4; ++v) {
                    int m = m0 + wm * 64 + fr * 16 + lkb * 4 + v;
                    int n = n0 + wn * 64 + fc * 16 + lr;
                    int t = m >> 2, b = m & 3;
                    int h = n >> 5, i = n & 31;
                    float y = acc[fr][fc][v];
                    float s = y / (1.f + __expf(-y));
                    dstF[(((size_t)(b * HH + h)) * T_LEN + t) * NS + i] = s;
                }
    }
}

// ---------------------------------------------------------------------------
// q projection, single fp16 MFMA (q is read-out-only): q = l2norm(silu(x@Wq^T)),
// fp16 store at [B][H][T][NS].
// ---------------------------------------------------------------------------
__global__ __launch_bounds__(256) void q_gemm_f16_kernel(
    const unsigned short* __restrict__ xf, const unsigned short* __restrict__ Wqf,
    unsigned short* __restrict__ dstH) {
    __shared__ __align__(16) unsigned short As[128 * 32];
    __shared__ __align__(16) unsigned short Bs[128 * 32];
    int m0 = blockIdx.y * 128, n0 = blockIdx.x * 128;

    const int tid  = threadIdx.x;
    const int lane = tid & 63;
    const int wave = tid >> 6;
    const int wm = wave >> 1, wn = wave & 1;
    const int lr = lane & 15, lkb = lane >> 4;

    f32x4 acc[4][4];
#pragma unroll
    for (int fr = 0; fr < 4; ++fr)
#pragma unroll
        for (int fc = 0; fc < 4; ++fc) acc[fr][fc] = (f32x4){0.f, 0.f, 0.f, 0.f};

    auto stage = [&](int kt) {
#pragma unroll
        for (int c = 0; c < 2; ++c) {
            int i = c * 256 + tid;
            int r = i >> 2, kk = (i & 3) << 3;
            gload_lds16(xf + (size_t)(m0 + r) * DIM + kt + kk, As + i * 8);
            gload_lds16(Wqf + (size_t)(n0 + r) * DIM + kt + kk, Bs + i * 8);
        }
    };

    stage(0);
    const int nk = DIM >> 5;
    for (int t = 0; t < nk; ++t) {
        __syncthreads();
        f16x8 af[4], bf[4];
#pragma unroll
        for (int f = 0; f < 4; ++f) {
            af[f] = *(const f16x8*)(As + (wm * 64 + f * 16 + lr) * 32 + lkb * 8);
            bf[f] = *(const f16x8*)(Bs + (wn * 64 + f * 16 + lr) * 32 + lkb * 8);
        }
#pragma unroll
        for (int fr = 0; fr < 4; ++fr)
#pragma unroll
            for (int fc = 0; fc < 4; ++fc)
                acc[fr][fc] = __builtin_amdgcn_mfma_f32_16x16x32_f16(
                    af[fr], bf[fc], acc[fr][fc], 0, 0, 0);
        __syncthreads();
        if (t + 1 < nk) stage((t + 1) << 5);
    }

#pragma unroll
    for (int fr = 0; fr < 4; ++fr)
#pragma unroll
        for (int hc = 0; hc < 2; ++hc)
#pragma unroll
            for (int v = 0; v < 4; ++v) {
                float yA = acc[fr][2 * hc][v];
                float yB = acc[fr][2 * hc + 1][v];
                float sA = yA / (1.f + __expf(-yA));
                float sB = yB / (1.f + __expf(-yB));
                float ss = fmaf(sA, sA, sB * sB);
                ss = dpp_sum16(ss);
                float sc = 1.f / fmaxf(sqrtf(ss), 1e-12f);
                int m = m0 + wm * 64 + fr * 16 + lkb * 4 + v;
                int t = m >> 2, b = m & 3;
                int h = ((n0 + wn * 64) >> 5) + hc;
                size_t ro = (((size_t)(b * HH + h)) * T_LEN + t) * NS;
                dstH[ro + lr]      = f2h(sA * sc);
                dstH[ro + lr + 16] = f2h(sB * sc);
            }
}

// ---------------------------------------------------------------------------
// Output GEMM (fp16): out = Sq @ Wout^T, f32 store.
// ---------------------------------------------------------------------------
__global__ __launch_bounds__(256) void out_gemm_kernel(
    const unsigned short* __restrict__ Sq, const unsigned short* __restrict__ Wo,
    float* __restrict__ out) {
    __shared__ __align__(16) unsigned short As[128 * 32];
    __shared__ __align__(16) unsigned short Bs[128 * 32];
    int m0 = blockIdx.y * 128, n0 = blockIdx.x * 128;

    const int tid  = threadIdx.x;
    const int lane = tid & 63;
    const int wave = tid >> 6;
    const int wm = wave >> 1, wn = wave & 1;
    const int lr = lane & 15, lkb = lane >> 4;

    f32x4 acc[4][4];
#pragma unroll
    for (int fr = 0; fr < 4; ++fr)
#pragma unroll
        for (int fc = 0; fc < 4; ++fc) acc[fr][fc] = (f32x4){0.f, 0.f, 0.f, 0.f};

    auto stage = [&](int kt) {
#pragma unroll
        for (int c = 0; c < 2; ++c) {
            int i = c * 256 + tid;
            int r = i >> 2, kk = (i & 3) << 3;
            gload_lds16(Sq + (size_t)(m0 + r) * KD + kt + kk, As + i * 8);
            gload_lds16(Wo + (size_t)(n0 + r) * KD + kt + kk, Bs + i * 8);
        }
    };

    stage(0);
    const int nk = KD >> 5;
    for (int t = 0; t < nk; ++t) {
        __syncthreads();
        f16x8 af[4], bf[4];
#pragma unroll
        for (int f = 0; f < 4; ++f) {
            af[f] = *(const f16x8*)(As + (wm * 64 + f * 16 + lr) * 32 + lkb * 8);
            bf[f] = *(const f16x8*)(Bs + (wn * 64 + f * 16 + lr) * 32 + lkb * 8);
        }
#pragma unroll
        for (int fr = 0; fr < 4; ++fr)
#pragma unroll
            for (int fc = 0; fc < 4; ++fc)
                acc[fr][fc] = __builtin_amdgcn_mfma_f32_16x16x32_f16(
                    af[fr], bf[fc], acc[fr][fc], 0, 0, 0);
        __syncthreads();
        if (t + 1 < nk) stage((t + 1) << 5);
    }

#pragma unroll
    for (int fr = 0; fr < 4; ++fr)
#pragma unroll
        for (int fc = 0; fc < 4; ++fc)
#pragma unroll
            for (int v = 0; v < 4; ++v) {
                int m = m0 + wm * 64 + fr * 16 + lkb * 4 + v;
                int n = n0 + wn * 64 + fc * 16 + lr;
                out[(size_t)m * DIM + n] = acc[fr][fc][v];
            }
}

// ---------------------------------------------------------------------------
// Sequential scan: 512 threads (8 waves) per (b,h); 16 lanes per column x
// 2 state elements per lane. LDS chunk ring (4-deep, staged 2 ahead, counted
// vmcnt) + in-chunk 4-step groups via inline-asm ds_read, lgkmcnt(13).
// Delayed-o dual reduction: o_t is reduced during step t+1 alongside r_{t+1}
// (independent DPP trees interleave) -> one DPP tree on the serial chain.
// ---------------------------------------------------------------------------
__global__ __launch_bounds__(512, 1) void scan_kernel(
    const float* __restrict__ kf, const unsigned short* __restrict__ qh,
    const float* __restrict__ vf, const float* __restrict__ decayb,
    const float* __restrict__ S0, unsigned short* __restrict__ Sq,
    float* __restrict__ Sout) {
    __shared__ __align__(16) float          kbuf[4][CH][NS];   // 8 KB
    __shared__ __align__(16) float          vbuf[4][CH][NS];   // 8 KB
    __shared__ __align__(16) unsigned short qbuf[4][CH][NS];   // 4 KB
    __shared__ __align__(16) float          dbuf[4][64];       // 1 KB

    const int bh = blockIdx.x;                 // 0..223  (= b*HH + h)
    const int b = bh / HH, h = bh - b * HH;
    const int tid = threadIdx.x;
    const int lane = tid & 63, wave = tid >> 6;
    const int col = tid >> 4;                  // 0..31 (column j)
    const int ii  = tid & 15;                  // 0..15 (lane within column)
    const int i0  = ii * 2;                    // state elements i0, i0+1

    const float* Sp = S0 + (size_t)bh * NS * NS;
    float s0 = Sp[(i0 + 0) * NS + col];
    float s1 = Sp[(i0 + 1) * NS + col];

    const size_t base  = (size_t)bh * T_LEN * NS;
    const size_t dbase = (size_t)bh * T_LEN;
    const size_t cbcol = (size_t)h * NS;       // Sq column base

    // per-lane LDS base offsets (slot 0)
    const unsigned kb0 = lds_off(&kbuf[0][0][0]) + (unsigned)i0 * 4;
    const unsigned qb0 = lds_off(&qbuf[0][0][0]) + (unsigned)i0 * 2;
    const unsigned vb0 = lds_off(&vbuf[0][0][0]) + (unsigned)col * 4;
    const unsigned db0 = lds_off(&dbuf[0][0]);

    // Wave-specialized chunk staging: waves 0-5 each issue ONE vm op/stage.
    auto stage = [&](int c) {
        int s = c & 3;
        if (wave == 0) {
            gload_lds16(kf + base + (size_t)c * 512 + lane * 4,
                        &kbuf[s][0][0] + lane * 4);
        } else if (wave == 1) {
            gload_lds16(kf + base + (size_t)c * 512 + 256 + lane * 4,
                        &kbuf[s][8][0] + lane * 4);
        } else if (wave == 2) {
            gload_lds16(vf + base + (size_t)c * 512 + lane * 4,
                        &vbuf[s][0][0] + lane * 4);
        } else if (wave == 3) {
            gload_lds16(vf + base + (size_t)c * 512 + 256 + lane * 4,
                        &vbuf[s][8][0] + lane * 4);
        } else if (wave == 4) {
            gload_lds16(qh + base + (size_t)c * 512 + lane * 8,
                        &qbuf[s][0][0] + lane * 8);
        } else if (wave == 5) {
            gload_lds4(decayb + dbase + (size_t)c * CH + lane,
                       &dbuf[s][0] + lane);    // tail lanes: junk, unused
        }
    };

    stage(0);
    stage(1);
    VMCNT(0);
    __builtin_amdgcn_s_barrier();

    float o_pend = 0.f;                        // un-reduced o of previous step

    for (int c = 0; c < NCHUNK; ++c) {
        if (c + 2 < NCHUNK) stage(c + 2);
        // Staging waves: outstanding = stage(c+1) + stage(c+2) + 16 Sq stores
        // of prior chunk = 18; stage(c) is older -> VMCNT(18) drains it.
        if (wave < 6) { VMCNT(18); }
        __builtin_amdgcn_s_barrier();
        SB;

        const int s = c & 3;
        const unsigned kb = kb0 + (unsigned)s * (CH * NS * 4);
        const unsigned qb = qb0 + (unsigned)s * (CH * NS * 2);
        const unsigned vb = vb0 + (unsigned)s * (CH * NS * 4);
        const unsigned db = db0 + (unsigned)s * 256;

        f32x2 kA[4], kB[4]; unsigned qA[4], qB[4]; float vA[4], vB[4];
        f32x4 dA, dB;

#define LDG(KK, QQ, VV, DV, g)                                          \
        KK[0] = dsr64f<((g) * 4 + 0) * 128>(kb);                        \
        KK[1] = dsr64f<((g) * 4 + 1) * 128>(kb);                        \
        KK[2] = dsr64f<((g) * 4 + 2) * 128>(kb);                        \
        KK[3] = dsr64f<((g) * 4 + 3) * 128>(kb);                        \
        QQ[0] = dsr32u<((g) * 4 + 0) * 64>(qb);                         \
        QQ[1] = dsr32u<((g) * 4 + 1) * 64>(qb);                         \
        QQ[2] = dsr32u<((g) * 4 + 2) * 64>(qb);                         \
        QQ[3] = dsr32u<((g) * 4 + 3) * 64>(qb);                         \
        VV[0] = dsr32f<((g) * 4 + 0) * 128>(vb);                        \
        VV[1] = dsr32f<((g) * 4 + 1) * 128>(vb);                        \
        VV[2] = dsr32f<((g) * 4 + 2) * 128>(vb);                        \
        VV[3] = dsr32f<((g) * 4 + 3) * 128>(vb);                        \
        DV    = dsr128<(g) * 16>(db);          /* broadcast: 4 decays */

#define CMP(KK, QQ, VV, DV, g)                                          \
        {                                                               \
            _Pragma("unroll")                                           \
            for (int p = 0; p < 4; ++p) {                               \
                const int t = c * CH + (g) * 4 + p;                     \
                float k0 = KK[p][0], k1 = KK[p][1];                     \
                float q0 = h2f((unsigned short)(QQ[p] & 0xffff));       \
                float q1 = h2f((unsigned short)(QQ[p] >> 16));          \
                float vj = VV[p];                                       \
                float d  = DV[p];                                       \
                float xr = fmaf(k1, s1, k0 * s0);                       \
                f32x2 rd = dpp_sum16x2(xr, o_pend);                     \
                if (ii == 0 && t > 0) {                                 \
                    size_t ro = ((size_t)(t - 1) * BB + b) * KD + cbcol;\
                    Sq[ro + col] = f2h(rd[1]);                          \
                }                                                       \
                float delta = vj - rd[0];                               \
                float a0 = fmaf(d, s0, k0 * delta);                     \
                float a1 = fmaf(d, s1, k1 * delta);                     \
                s0 += tanh_fast(a0); s1 += tanh_fast(a1);               \
                o_pend = fmaf(q1, s1, q0 * s0);                         \
            }                                                           \
        }

        // 4-step group pipeline: asm ds_reads can't be sunk; counted
        // lgkmcnt(13) = wait group done while next group's 13 stay in flight.
        LDG(kA, qA, vA, dA, 0);
        LDG(kB, qB, vB, dB, 1);
        LGKM(13); SB;                 // A ready (B's 13 still in flight)
        CMP(kA, qA, vA, dA, 0);
        LDG(kA, qA, vA, dA, 2);
        LGKM(13); SB;                 // B ready (A2 in flight)
        CMP(kB, qB, vB, dB, 1);
        LDG(kB, qB, vB, dB, 3);
        LGKM(13); SB;                 // A2 ready (B2 in flight)
        CMP(kA, qA, vA, dA, 2);
        LGKM(0); SB;                  // B2 ready
        CMP(kB, qB, vB, dB, 3);
#undef LDG
#undef CMP
    }

    // Flush the final pending o (t = T_LEN-1).
    {
        float oo = dpp_sum16(o_pend);
        if (ii == 0) {
            size_t ro = ((size_t)(T_LEN - 1) * BB + b) * KD + cbcol;
            Sq[ro + col] = f2h(oo);
        }
    }

    float* so = Sout + (size_t)bh * NS * NS;
    so[(i0 + 0) * NS + col] = s0;
    so[(i0 + 1) * NS + col] = s1;
}

// ---------------------------------------------------------------------------
extern "C" void kernel_launch(void* const* d_in, const int* in_sizes, int n_in,
                              void* d_out, int out_size, void* d_ws, size_t ws_size,
                              hipStream_t stream) {
    const float* x       = (const float*)d_in[0];
    const float* S0      = (const float*)d_in[1];
    const float* Wq      = (const float*)d_in[2];
    const float* Wk      = (const float*)d_in[3];
    const float* Wv      = (const float*)d_in[4];
    const float* Wa      = (const float*)d_in[5];
    const float* A_log   = (const float*)d_in[6];
    const float* dt_bias = (const float*)d_in[7];
    const float* Wout    = (const float*)d_in[8];

    float* out  = (float*)d_out;
    float* Sout = out + (size_t)T_LEN * BB * DIM;

    // --- workspace layout (~165 MB peak) ---
    char* w = (char*)d_ws;
    auto alloc = [&](size_t bytes) {
        char* p = w; w += (bytes + 255) & ~(size_t)255; return p;
    };
    unsigned short* xh  = (unsigned short*)alloc((size_t)MROWS * DIM * 2);  // 16.8 MB
    unsigned short* xl  = (unsigned short*)alloc((size_t)MROWS * DIM * 2);  // 16.8 MB
    unsigned short* Wbh = (unsigned short*)alloc((size_t)KD * DIM * 2);     // 3.67 MB (reused)
    unsigned short* Wbl = (unsigned short*)alloc((size_t)KD * DIM * 2);     // 3.67 MB (reused)
    unsigned short* Wah = (unsigned short*)alloc((size_t)HH * DIM * 2);     // 0.11 MB
    unsigned short* Wal = (unsigned short*)alloc((size_t)HH * DIM * 2);     // 0.11 MB
    float* kf           = (float*)alloc((size_t)MROWS * KD * 4);            // 58.7 MB
    float* vf           = (float*)alloc((size_t)MROWS * KD * 4);            // 58.7 MB
    unsigned short* Woh = (unsigned short*)alloc((size_t)DIM * KD * 2);     // 3.67 MB
    // Aliases: Sq (fp16) over xh/xl (x dead after last proj GEMM);
    //          x-fp16 over vf head (dead once v-proj runs, after q-proj).
    unsigned short* Sq   = xh;
    unsigned short* xf16 = (unsigned short*)vf;

    // --- d_out head as scratch for q (fp16) + decay: dead before out GEMM ---
    unsigned short* qh  = (unsigned short*)d_out;                 // 29.36 MB
    float* decayb       = (float*)((char*)d_out + (size_t)MROWS * KD * 2); // 1.83 MB

    // 1) x -> bf16 hi/lo + fp16 (fp16 copy aliased in vf head)
    {
        int n8 = (int)((size_t)MROWS * DIM / 8);
        cast_split3_kernel<<<(n8 + 255) / 256, 256, 0, stream>>>(x, xh, xl, xf16, n8);
    }
    // 2) q projection (single fp16 MFMA, fused l2norm): Wq fp16 staged in Wbh
    {
        int n8 = (int)((size_t)KD * DIM / 8);
        cast_half_kernel<<<(n8 + 255) / 256, 256, 0, stream>>>(Wq, Wbh, n8);
        q_gemm_f16_kernel<<<dim3(14, 64), 256, 0, stream>>>(xf16, Wbh, qh);
    }
    // 3) k projection (fused l2norm) + decay (tile 14), split-bf16
    {
        int n8 = (int)((size_t)KD * DIM / 8);
        cast_split_kernel<<<(n8 + 255) / 256, 256, 0, stream>>>(Wk, Wbh, Wbl, n8);
        int n8a = (int)((size_t)HH * DIM / 8);
        cast_split_kernel<<<(n8a + 255) / 256, 256, 0, stream>>>(Wa, Wah, Wal, n8a);
        proj_split_kernel<<<dim3(15, 64), 256, 0, stream>>>(
            xh, xl, Wbh, Wbl, Wah, Wal, A_log, dt_bias, kf, decayb, 1);
    }
    // 4) v projection (no norm; overwrites xf16 alias -- dead after q-proj)
    {
        int n8 = (int)((size_t)KD * DIM / 8);
        cast_split_kernel<<<(n8 + 255) / 256, 256, 0, stream>>>(Wv, Wbh, Wbl, n8);
        proj_split_kernel<<<dim3(14, 64), 256, 0, stream>>>(
            xh, xl, Wbh, Wbl, Wah, Wal, A_log, dt_bias, vf, decayb, 0);
    }
    // 5) Wout -> fp16
    {
        int n8 = (int)((size_t)DIM * KD / 8);
        cast_half_kernel<<<(n8 + 255) / 256, 256, 0, stream>>>(Wout, Woh, n8);
    }
    // 6) scan (512 threads per (b,h): 16 lanes/col x 2 elems, delayed-o)
    scan_kernel<<<BB * HH, 512, 0, stream>>>(kf, qh, vf, decayb, S0, Sq, Sout);
    // 7) output GEMM
    out_gemm_kernel<<<dim3(8, 64), 256, 0, stream>>>(Sq, Woh, out);
}

// Round 14
// 663.294 us; speedup vs baseline: 1.4093x; 1.0796x over previous
//
#include <hip/hip_runtime.h>

// ---------------------------------------------------------------------------
// E89 ResidualStateCell.
// Precision: k,v,decay (feed the recurrence) via split-bf16 (hi+lo) MFMA ->
// fp32; q,Sq,Wout (read-out only) via fp16 MFMA. Scan fp32 with fast tanh.
// Scan: 512 thr/bh (16 lanes/col x 2 elems), 4-deep LDS ring CH=32, counted
// vmcnt(4), inline-asm ds_read groups w/ lgkmcnt(13), delayed-o dual DPP
// reduction, and LDS-buffered Sq (wave 6 flushes chunk c-2 as dwordx4).
// Dispatch chain: megacast (all casts in 1) -> q-gemm -> fused k/decay/v
// proj -> scan -> out-gemm  (5 launches).
// Layout: k,v,q transposed [B][H][T][NS], decay [B][H][T].
// Memory: ws ~171 MB. q fp16 + decay live in d_out head (dead before the
// final out-GEMM overwrites it). x-fp16 aliases vf head; Sq aliases xh/xl.
// ---------------------------------------------------------------------------

typedef __attribute__((ext_vector_type(8))) __bf16 bf16x8;
typedef __attribute__((ext_vector_type(8))) _Float16 f16x8;
typedef __attribute__((ext_vector_type(4))) float f32x4;
typedef __attribute__((ext_vector_type(2))) float f32x2;

#define T_LEN 2048
#define BB 4
#define HH 56
#define NS 32
#define DIM 1024
#define KD 1792            // H*NS
#define MROWS 8192         // T_LEN*BB
#define CH 32              // scan chunk (steps)
#define NCHUNK (T_LEN / CH)

#define VMCNT(N) asm volatile("s_waitcnt vmcnt(" #N ")" ::: "memory")
#define LGKM(N)  asm volatile("s_waitcnt lgkmcnt(" #N ")" ::: "memory")
#define SB       __builtin_amdgcn_sched_barrier(0)

__device__ __forceinline__ float bf2f(unsigned short u) {
    return __uint_as_float(((unsigned int)u) << 16);
}
__device__ __forceinline__ unsigned short f2bf(float f) {
    unsigned int u = __float_as_uint(f);
    u += 0x7fffu + ((u >> 16) & 1u);          // round-to-nearest-even
    return (unsigned short)(u >> 16);
}
__device__ __forceinline__ unsigned short f2h(float f) {
    union { _Float16 h; unsigned short u; } cv;
    cv.h = (_Float16)f;                       // RNE
    return cv.u;
}
__device__ __forceinline__ float h2f(unsigned short u) {
    union { unsigned short u; _Float16 h; } cv;
    cv.u = u;
    return (float)cv.h;
}

// tanh via v_exp_f32 (2^x): tanh(x) = 1 - 2/(1+2^(2*log2e*x))
__device__ __forceinline__ float tanh_fast(float x) {
    float e = __builtin_amdgcn_exp2f(x * 2.885390081777927f);
    float r = __builtin_amdgcn_rcpf(e + 1.0f);
    return fmaf(-2.0f, r, 1.0f);
}

// Sum across each aligned group of 16 lanes, pure-VALU DPP butterfly.
__device__ __forceinline__ float dpp_sum16(float x) {
    int t;
    t = __builtin_amdgcn_update_dpp(0, __float_as_int(x), 0xB1, 0xf, 0xf, true);
    x += __int_as_float(t);
    t = __builtin_amdgcn_update_dpp(0, __float_as_int(x), 0x4E, 0xf, 0xf, true);
    x += __int_as_float(t);
    t = __builtin_amdgcn_update_dpp(0, __float_as_int(x), 0x141, 0xf, 0xf, true);
    x += __int_as_float(t);
    t = __builtin_amdgcn_update_dpp(0, __float_as_int(x), 0x140, 0xf, 0xf, true);
    x += __int_as_float(t);
    return x;
}

// Dual 16-lane sum: two independent DPP trees, interleaved for ILP.
__device__ __forceinline__ f32x2 dpp_sum16x2(float a, float b) {
    int ta, tb;
    ta = __builtin_amdgcn_update_dpp(0, __float_as_int(a), 0xB1, 0xf, 0xf, true);
    tb = __builtin_amdgcn_update_dpp(0, __float_as_int(b), 0xB1, 0xf, 0xf, true);
    a += __int_as_float(ta); b += __int_as_float(tb);
    ta = __builtin_amdgcn_update_dpp(0, __float_as_int(a), 0x4E, 0xf, 0xf, true);
    tb = __builtin_amdgcn_update_dpp(0, __float_as_int(b), 0x4E, 0xf, 0xf, true);
    a += __int_as_float(ta); b += __int_as_float(tb);
    ta = __builtin_amdgcn_update_dpp(0, __float_as_int(a), 0x141, 0xf, 0xf, true);
    tb = __builtin_amdgcn_update_dpp(0, __float_as_int(b), 0x141, 0xf, 0xf, true);
    a += __int_as_float(ta); b += __int_as_float(tb);
    ta = __builtin_amdgcn_update_dpp(0, __float_as_int(a), 0x140, 0xf, 0xf, true);
    tb = __builtin_amdgcn_update_dpp(0, __float_as_int(b), 0x140, 0xf, 0xf, true);
    a += __int_as_float(ta); b += __int_as_float(tb);
    return (f32x2){a, b};
}

__device__ __forceinline__ void gload_lds16(const void* g, void* l) {
    __builtin_amdgcn_global_load_lds(
        (const __attribute__((address_space(1))) unsigned int*)g,
        (__attribute__((address_space(3))) unsigned int*)l, 16, 0, 0);
}
__device__ __forceinline__ void gload_lds4(const void* g, void* l) {
    __builtin_amdgcn_global_load_lds(
        (const __attribute__((address_space(1))) unsigned int*)g,
        (__attribute__((address_space(3))) unsigned int*)l, 4, 0, 0);
}

// LDS byte offset of a generic pointer to __shared__ memory.
__device__ __forceinline__ unsigned lds_off(const void* p) {
    return (unsigned)(unsigned long long)
        (const __attribute__((address_space(3))) char*)p;
}

// Inline-asm LDS reads (opaque to the compiler: cannot be sunk/reordered).
template <int OFF>
__device__ __forceinline__ f32x4 dsr128(unsigned a) {
    f32x4 r;
    asm volatile("ds_read_b128 %0, %1 offset:%2" : "=v"(r) : "v"(a), "n"(OFF));
    return r;
}
template <int OFF>
__device__ __forceinline__ f32x2 dsr64f(unsigned a) {
    f32x2 r;
    asm volatile("ds_read_b64 %0, %1 offset:%2" : "=v"(r) : "v"(a), "n"(OFF));
    return r;
}
template <int OFF>
__device__ __forceinline__ unsigned dsr32u(unsigned a) {
    unsigned r;
    asm volatile("ds_read_b32 %0, %1 offset:%2" : "=v"(r) : "v"(a), "n"(OFF));
    return r;
}
template <int OFF>
__device__ __forceinline__ float dsr32f(unsigned a) {
    float r;
    asm volatile("ds_read_b32 %0, %1 offset:%2" : "=v"(r) : "v"(a), "n"(OFF));
    return r;
}

// ---------------------------------------------------------------------------
// Megacast: all input casts in one launch. Each thread handles 8 elements.
// Ranges: x triple | Wk split | Wv split | Wa split | Wq fp16 | Wout fp16.
// ---------------------------------------------------------------------------
__device__ __forceinline__ void do_split8(const float* in, unsigned short* hi,
                                          unsigned short* lo, int i) {
    const float4* p = (const float4*)in + (size_t)i * 2;
    float4 a = p[0], b = p[1];
    float xs[8] = {a.x, a.y, a.z, a.w, b.x, b.y, b.z, b.w};
    unsigned int ho[4], lv[4];
#pragma unroll
    for (int c = 0; c < 4; ++c) {
        unsigned short h0 = f2bf(xs[2 * c]);
        unsigned short h1 = f2bf(xs[2 * c + 1]);
        unsigned short l0 = f2bf(xs[2 * c] - bf2f(h0));
        unsigned short l1 = f2bf(xs[2 * c + 1] - bf2f(h1));
        ho[c] = (unsigned int)h0 | ((unsigned int)h1 << 16);
        lv[c] = (unsigned int)l0 | ((unsigned int)l1 << 16);
    }
    ((uint4*)hi)[i] = (uint4){ho[0], ho[1], ho[2], ho[3]};
    ((uint4*)lo)[i] = (uint4){lv[0], lv[1], lv[2], lv[3]};
}
__device__ __forceinline__ void do_half8(const float* in, unsigned short* out, int i) {
    const float4* p = (const float4*)in + (size_t)i * 2;
    float4 a = p[0], b = p[1];
    uint4 o;
    o.x = (unsigned int)f2h(a.x) | ((unsigned int)f2h(a.y) << 16);
    o.y = (unsigned int)f2h(a.z) | ((unsigned int)f2h(a.w) << 16);
    o.z = (unsigned int)f2h(b.x) | ((unsigned int)f2h(b.y) << 16);
    o.w = (unsigned int)f2h(b.z) | ((unsigned int)f2h(b.w) << 16);
    ((uint4*)out)[i] = o;
}

__global__ void megacast_kernel(
    const float* __restrict__ x, unsigned short* __restrict__ xh,
    unsigned short* __restrict__ xl, unsigned short* __restrict__ xf16,
    const float* __restrict__ Wk, unsigned short* __restrict__ Wkh,
    unsigned short* __restrict__ Wkl,
    const float* __restrict__ Wv, unsigned short* __restrict__ Wvh,
    unsigned short* __restrict__ Wvl,
    const float* __restrict__ Wa, unsigned short* __restrict__ Wah,
    unsigned short* __restrict__ Wal,
    const float* __restrict__ Wq, unsigned short* __restrict__ Wqh16,
    const float* __restrict__ Wout, unsigned short* __restrict__ Woh) {
    int i = blockIdx.x * blockDim.x + threadIdx.x;
    const int N0 = MROWS * DIM / 8;            // x
    const int N1 = KD * DIM / 8;               // Wk/Wv/Wq/Wout
    const int N3 = HH * DIM / 8;               // Wa
    if (i < N0) {
        // x: bf16 hi/lo + fp16
        const float4* p = (const float4*)x + (size_t)i * 2;
        float4 a = p[0], b = p[1];
        float xs[8] = {a.x, a.y, a.z, a.w, b.x, b.y, b.z, b.w};
        unsigned int ho[4], lv[4], hv[4];
#pragma unroll
        for (int c = 0; c < 4; ++c) {
            unsigned short h0 = f2bf(xs[2 * c]);
            unsigned short h1 = f2bf(xs[2 * c + 1]);
            unsigned short l0 = f2bf(xs[2 * c] - bf2f(h0));
            unsigned short l1 = f2bf(xs[2 * c + 1] - bf2f(h1));
            ho[c] = (unsigned int)h0 | ((unsigned int)h1 << 16);
            lv[c] = (unsigned int)l0 | ((unsigned int)l1 << 16);
            hv[c] = (unsigned int)f2h(xs[2 * c]) |
                    ((unsigned int)f2h(xs[2 * c + 1]) << 16);
        }
        ((uint4*)xh)[i]   = (uint4){ho[0], ho[1], ho[2], ho[3]};
        ((uint4*)xl)[i]   = (uint4){lv[0], lv[1], lv[2], lv[3]};
        ((uint4*)xf16)[i] = (uint4){hv[0], hv[1], hv[2], hv[3]};
        return;
    }
    i -= N0;
    if (i < N1) { do_split8(Wk, Wkh, Wkl, i); return; }
    i -= N1;
    if (i < N1) { do_split8(Wv, Wvh, Wvl, i); return; }
    i -= N1;
    if (i < N3) { do_split8(Wa, Wah, Wal, i); return; }
    i -= N3;
    if (i < N1) { do_half8(Wq, Wqh16, i); return; }
    i -= N1;
    if (i < N1) { do_half8(Wout, Woh, i); }
}
#define MEGACAST_ITEMS (MROWS * DIM / 8 + 4 * (KD * DIM / 8) + HH * DIM / 8)

// ---------------------------------------------------------------------------
// Split MFMA GEMM core: Y[m,n] = sum_k A[m,k]*B[n,k], A=Ah+Al, B=Bh+Bl.
// 128x128 tile, BK=32, 256 threads = 4 waves (2x2), 16x16x32 bf16 MFMA x3.
// ---------------------------------------------------------------------------
__device__ __forceinline__ void gemm_split(
    const unsigned short* __restrict__ Ah, const unsigned short* __restrict__ Al,
    const unsigned short* __restrict__ Bh, const unsigned short* __restrict__ Bl,
    int m0, int n0, int K, int bmax,
    unsigned short* AsH, unsigned short* AsL,
    unsigned short* BsH, unsigned short* BsL,
    f32x4 (&acc)[4][4]) {
    const int tid  = threadIdx.x;
    const int lane = tid & 63;
    const int wave = tid >> 6;
    const int wm = wave >> 1, wn = wave & 1;
    const int lr = lane & 15, lkb = lane >> 4;

#pragma unroll
    for (int fr = 0; fr < 4; ++fr)
#pragma unroll
        for (int fc = 0; fc < 4; ++fc) acc[fr][fc] = (f32x4){0.f, 0.f, 0.f, 0.f};

    auto stage = [&](int kt) {
#pragma unroll
        for (int c = 0; c < 2; ++c) {
            int i = c * 256 + tid;
            int r = i >> 2, kk = (i & 3) << 3;
            size_t ao = (size_t)(m0 + r) * K + kt + kk;
            int br = n0 + r; if (br > bmax) br = bmax;
            size_t bo = (size_t)br * K + kt + kk;
            gload_lds16(Ah + ao, AsH + i * 8);
            gload_lds16(Al + ao, AsL + i * 8);
            gload_lds16(Bh + bo, BsH + i * 8);
            gload_lds16(Bl + bo, BsL + i * 8);
        }
    };

    stage(0);
    const int nk = K >> 5;
    for (int t = 0; t < nk; ++t) {
        __syncthreads();                       // drains vmcnt -> LDS tiles ready
        bf16x8 ah[4], al[4], bh[4], bl[4];
#pragma unroll
        for (int f = 0; f < 4; ++f) {
            int ai = (wm * 64 + f * 16 + lr) * 32 + lkb * 8;
            int bi = (wn * 64 + f * 16 + lr) * 32 + lkb * 8;
            ah[f] = *(const bf16x8*)(AsH + ai);
            al[f] = *(const bf16x8*)(AsL + ai);
            bh[f] = *(const bf16x8*)(BsH + bi);
            bl[f] = *(const bf16x8*)(BsL + bi);
        }
#pragma unroll
        for (int fr = 0; fr < 4; ++fr)
#pragma unroll
            for (int fc = 0; fc < 4; ++fc) {
                acc[fr][fc] = __builtin_amdgcn_mfma_f32_16x16x32_bf16(
                    ah[fr], bh[fc], acc[fr][fc], 0, 0, 0);
                acc[fr][fc] = __builtin_amdgcn_mfma_f32_16x16x32_bf16(
                    ah[fr], bl[fc], acc[fr][fc], 0, 0, 0);
                acc[fr][fc] = __builtin_amdgcn_mfma_f32_16x16x32_bf16(
                    al[fr], bh[fc], acc[fr][fc], 0, 0, 0);
            }
        __syncthreads();                       // all waves done reading LDS
        if (t + 1 < nk) stage((t + 1) << 5);
    }
}

// ---------------------------------------------------------------------------
// Fused k/decay/v projection.  Row m = t*BB + b.
// tile 0..13 : k  (silu + fused l2norm) -> fp32 kf  [B][H][T][NS]
// tile 14    : decay                    -> fp32 decayb [B][H][T]
// tile 15..28: v  (silu)                -> fp32 vf  [B][H][T][NS]
// ---------------------------------------------------------------------------
__global__ __launch_bounds__(256) void kv_proj_kernel(
    const unsigned short* __restrict__ xh, const unsigned short* __restrict__ xl,
    const unsigned short* __restrict__ Wkh, const unsigned short* __restrict__ Wkl,
    const unsigned short* __restrict__ Wvh, const unsigned short* __restrict__ Wvl,
    const unsigned short* __restrict__ Wah, const unsigned short* __restrict__ Wal,
    const float* __restrict__ A_log, const float* __restrict__ dt_bias,
    float* __restrict__ kf, float* __restrict__ vf,
    float* __restrict__ decayb) {
    __shared__ __align__(16) unsigned short AsH[128 * 32];
    __shared__ __align__(16) unsigned short AsL[128 * 32];
    __shared__ __align__(16) unsigned short BsH[128 * 32];
    __shared__ __align__(16) unsigned short BsL[128 * 32];

    const int tile = blockIdx.x;               // 0..28
    int mode; const unsigned short *Bh, *Bl; int n0;
    if (tile < 14)       { mode = 0; Bh = Wkh; Bl = Wkl; n0 = tile * 128; }
    else if (tile == 14) { mode = 1; Bh = Wah; Bl = Wal; n0 = 0; }
    else                 { mode = 2; Bh = Wvh; Bl = Wvl; n0 = (tile - 15) * 128; }
    int m0 = blockIdx.y * 128;
    int bmax = (mode == 1) ? (HH - 1) : (KD - 1);

    f32x4 acc[4][4];
    gemm_split(xh, xl, Bh, Bl, m0, n0, DIM, bmax, AsH, AsL, BsH, BsL, acc);

    const int lane = threadIdx.x & 63, wave = threadIdx.x >> 6;
    const int wm = wave >> 1, wn = wave & 1, lr = lane & 15, lkb = lane >> 4;

    if (mode == 1) {
#pragma unroll
        for (int fr = 0; fr < 4; ++fr)
#pragma unroll
            for (int fc = 0; fc < 4; ++fc)
#pragma unroll
                for (int v = 0; v < 4; ++v) {
                    int m = m0 + wm * 64 + fr * 16 + lkb * 4 + v;
                    int n = n0 + wn * 64 + fc * 16 + lr;
                    int t = m >> 2, b = m & 3;
                    if (n < HH) {
                        float z = acc[fr][fc][v] + dt_bias[n];
                        float sp = (z > 20.f) ? z : log1pf(__expf(z));
                        decayb[((size_t)(b * HH + n)) * T_LEN + t] =
                            __expf(-__expf(A_log[n]) * sp);
                    }
                }
        return;
    }

    if (mode == 0) {
        // k: silu + fused l2norm over each head's 32 columns.
#pragma unroll
        for (int fr = 0; fr < 4; ++fr)
#pragma unroll
            for (int hc = 0; hc < 2; ++hc)
#pragma unroll
                for (int v = 0; v < 4; ++v) {
                    float yA = acc[fr][2 * hc][v];
                    float yB = acc[fr][2 * hc + 1][v];
                    float sA = yA / (1.f + __expf(-yA));
                    float sB = yB / (1.f + __expf(-yB));
                    float ss = fmaf(sA, sA, sB * sB);
                    ss = dpp_sum16(ss);            // sum over the head's 32 cols
                    float sc = 1.f / fmaxf(sqrtf(ss), 1e-12f);
                    int m = m0 + wm * 64 + fr * 16 + lkb * 4 + v;
                    int t = m >> 2, b = m & 3;
                    int h = ((n0 + wn * 64) >> 5) + hc;
                    size_t ro = (((size_t)(b * HH + h)) * T_LEN + t) * NS;
                    kf[ro + lr]      = sA * sc;
                    kf[ro + lr + 16] = sB * sc;
                }
    } else {
        // v: silu only
#pragma unroll
        for (int fr = 0; fr < 4; ++fr)
#pragma unroll
            for (int fc = 0; fc < 4; ++fc)
#pragma unroll
                for (int v = 0; v < 4; ++v) {
                    int m = m0 + wm * 64 + fr * 16 + lkb * 4 + v;
                    int n = n0 + wn * 64 + fc * 16 + lr;
                    int t = m >> 2, b = m & 3;
                    int h = n >> 5, i = n & 31;
                    float y = acc[fr][fc][v];
                    float s = y / (1.f + __expf(-y));
                    vf[(((size_t)(b * HH + h)) * T_LEN + t) * NS + i] = s;
                }
    }
}

// ---------------------------------------------------------------------------
// q projection, single fp16 MFMA (q is read-out-only): q = l2norm(silu(x@Wq^T)),
// fp16 store at [B][H][T][NS].
// ---------------------------------------------------------------------------
__global__ __launch_bounds__(256) void q_gemm_f16_kernel(
    const unsigned short* __restrict__ xf, const unsigned short* __restrict__ Wqf,
    unsigned short* __restrict__ dstH) {
    __shared__ __align__(16) unsigned short As[128 * 32];
    __shared__ __align__(16) unsigned short Bs[128 * 32];
    int m0 = blockIdx.y * 128, n0 = blockIdx.x * 128;

    const int tid  = threadIdx.x;
    const int lane = tid & 63;
    const int wave = tid >> 6;
    const int wm = wave >> 1, wn = wave & 1;
    const int lr = lane & 15, lkb = lane >> 4;

    f32x4 acc[4][4];
#pragma unroll
    for (int fr = 0; fr < 4; ++fr)
#pragma unroll
        for (int fc = 0; fc < 4; ++fc) acc[fr][fc] = (f32x4){0.f, 0.f, 0.f, 0.f};

    auto stage = [&](int kt) {
#pragma unroll
        for (int c = 0; c < 2; ++c) {
            int i = c * 256 + tid;
            int r = i >> 2, kk = (i & 3) << 3;
            gload_lds16(xf + (size_t)(m0 + r) * DIM + kt + kk, As + i * 8);
            gload_lds16(Wqf + (size_t)(n0 + r) * DIM + kt + kk, Bs + i * 8);
        }
    };

    stage(0);
    const int nk = DIM >> 5;
    for (int t = 0; t < nk; ++t) {
        __syncthreads();
        f16x8 af[4], bf[4];
#pragma unroll
        for (int f = 0; f < 4; ++f) {
            af[f] = *(const f16x8*)(As + (wm * 64 + f * 16 + lr) * 32 + lkb * 8);
            bf[f] = *(const f16x8*)(Bs + (wn * 64 + f * 16 + lr) * 32 + lkb * 8);
        }
#pragma unroll
        for (int fr = 0; fr < 4; ++fr)
#pragma unroll
            for (int fc = 0; fc < 4; ++fc)
                acc[fr][fc] = __builtin_amdgcn_mfma_f32_16x16x32_f16(
                    af[fr], bf[fc], acc[fr][fc], 0, 0, 0);
        __syncthreads();
        if (t + 1 < nk) stage((t + 1) << 5);
    }

#pragma unroll
    for (int fr = 0; fr < 4; ++fr)
#pragma unroll
        for (int hc = 0; hc < 2; ++hc)
#pragma unroll
            for (int v = 0; v < 4; ++v) {
                float yA = acc[fr][2 * hc][v];
                float yB = acc[fr][2 * hc + 1][v];
                float sA = yA / (1.f + __expf(-yA));
                float sB = yB / (1.f + __expf(-yB));
                float ss = fmaf(sA, sA, sB * sB);
                ss = dpp_sum16(ss);
                float sc = 1.f / fmaxf(sqrtf(ss), 1e-12f);
                int m = m0 + wm * 64 + fr * 16 + lkb * 4 + v;
                int t = m >> 2, b = m & 3;
                int h = ((n0 + wn * 64) >> 5) + hc;
                size_t ro = (((size_t)(b * HH + h)) * T_LEN + t) * NS;
                dstH[ro + lr]      = f2h(sA * sc);
                dstH[ro + lr + 16] = f2h(sB * sc);
            }
}

// ---------------------------------------------------------------------------
// Output GEMM (fp16): out = Sq @ Wout^T, f32 store.
// ---------------------------------------------------------------------------
__global__ __launch_bounds__(256) void out_gemm_kernel(
    const unsigned short* __restrict__ Sq, const unsigned short* __restrict__ Wo,
    float* __restrict__ out) {
    __shared__ __align__(16) unsigned short As[128 * 32];
    __shared__ __align__(16) unsigned short Bs[128 * 32];
    int m0 = blockIdx.y * 128, n0 = blockIdx.x * 128;

    const int tid  = threadIdx.x;
    const int lane = tid & 63;
    const int wave = tid >> 6;
    const int wm = wave >> 1, wn = wave & 1;
    const int lr = lane & 15, lkb = lane >> 4;

    f32x4 acc[4][4];
#pragma unroll
    for (int fr = 0; fr < 4; ++fr)
#pragma unroll
        for (int fc = 0; fc < 4; ++fc) acc[fr][fc] = (f32x4){0.f, 0.f, 0.f, 0.f};

    auto stage = [&](int kt) {
#pragma unroll
        for (int c = 0; c < 2; ++c) {
            int i = c * 256 + tid;
            int r = i >> 2, kk = (i & 3) << 3;
            gload_lds16(Sq + (size_t)(m0 + r) * KD + kt + kk, As + i * 8);
            gload_lds16(Wo + (size_t)(n0 + r) * KD + kt + kk, Bs + i * 8);
        }
    };

    stage(0);
    const int nk = KD >> 5;
    for (int t = 0; t < nk; ++t) {
        __syncthreads();
        f16x8 af[4], bf[4];
#pragma unroll
        for (int f = 0; f < 4; ++f) {
            af[f] = *(const f16x8*)(As + (wm * 64 + f * 16 + lr) * 32 + lkb * 8);
            bf[f] = *(const f16x8*)(Bs + (wn * 64 + f * 16 + lr) * 32 + lkb * 8);
        }
#pragma unroll
        for (int fr = 0; fr < 4; ++fr)
#pragma unroll
            for (int fc = 0; fc < 4; ++fc)
                acc[fr][fc] = __builtin_amdgcn_mfma_f32_16x16x32_f16(
                    af[fr], bf[fc], acc[fr][fc], 0, 0, 0);
        __syncthreads();
        if (t + 1 < nk) stage((t + 1) << 5);
    }

#pragma unroll
    for (int fr = 0; fr < 4; ++fr)
#pragma unroll
        for (int fc = 0; fc < 4; ++fc)
#pragma unroll
            for (int v = 0; v < 4; ++v) {
                int m = m0 + wm * 64 + fr * 16 + lkb * 4 + v;
                int n = n0 + wn * 64 + fc * 16 + lr;
                out[(size_t)m * DIM + n] = acc[fr][fc][v];
            }
}

// ---------------------------------------------------------------------------
// Sequential scan: 512 threads (8 waves) per (b,h); 16 lanes/col x 2 elems.
// CH=32 chunks, 4-deep LDS ring staged 2 ahead (waves 0-5, 2 gload each,
// counted VMCNT(4)); in-chunk 4-step groups via asm ds_read + lgkmcnt(13);
// delayed-o dual DPP reduction; Sq buffered in LDS obuf (4-slot), flushed
// chunk-wise by wave 6 as contiguous dwordx4 stores (cols contiguous in Sq).
// ---------------------------------------------------------------------------
__global__ __launch_bounds__(512, 1) void scan_kernel(
    const float* __restrict__ kf, const unsigned short* __restrict__ qh,
    const float* __restrict__ vf, const float* __restrict__ decayb,
    const float* __restrict__ S0, unsigned short* __restrict__ Sq,
    float* __restrict__ Sout) {
    __shared__ __align__(16) float          kbuf[4][CH][NS];   // 16 KB
    __shared__ __align__(16) float          vbuf[4][CH][NS];   // 16 KB
    __shared__ __align__(16) unsigned short qbuf[4][CH][NS];   // 8 KB
    __shared__ __align__(16) float          dbuf[4][64];       // 1 KB
    __shared__ __align__(16) unsigned short obuf[4][CH][NS];   // 8 KB

    const int bh = blockIdx.x;                 // 0..223  (= b*HH + h)
    const int b = bh / HH, h = bh - b * HH;
    const int tid = threadIdx.x;
    const int lane = tid & 63, wave = tid >> 6;
    const int col = tid >> 4;                  // 0..31 (column j)
    const int ii  = tid & 15;                  // 0..15 (lane within column)
    const int i0  = ii * 2;                    // state elements i0, i0+1

    const float* Sp = S0 + (size_t)bh * NS * NS;
    float s0 = Sp[(i0 + 0) * NS + col];
    float s1 = Sp[(i0 + 1) * NS + col];

    const size_t base  = (size_t)bh * T_LEN * NS;
    const size_t dbase = (size_t)bh * T_LEN;
    const size_t cbcol = (size_t)h * NS;       // Sq column base

    // per-lane LDS base offsets (slot 0)
    const unsigned kb0 = lds_off(&kbuf[0][0][0]) + (unsigned)i0 * 4;
    const unsigned qb0 = lds_off(&qbuf[0][0][0]) + (unsigned)i0 * 2;
    const unsigned vb0 = lds_off(&vbuf[0][0][0]) + (unsigned)col * 4;
    const unsigned db0 = lds_off(&dbuf[0][0]);

    // Wave-specialized chunk staging (CH=32): waves 0-5, two 16B ops each
    // (wave 5: one 4B op). Per-wave outstanding <= 2 per stage.
    auto stage = [&](int c) {
        int s = c & 3;
        if (wave == 0) {
            const float* src = kf + base + (size_t)c * (CH * NS);
            gload_lds16(src + lane * 4,       &kbuf[s][0][0] + lane * 4);
            gload_lds16(src + 256 + lane * 4, &kbuf[s][8][0] + lane * 4);
        } else if (wave == 1) {
            const float* src = kf + base + (size_t)c * (CH * NS);
            gload_lds16(src + 512 + lane * 4, &kbuf[s][16][0] + lane * 4);
            gload_lds16(src + 768 + lane * 4, &kbuf[s][24][0] + lane * 4);
        } else if (wave == 2) {
            const float* src = vf + base + (size_t)c * (CH * NS);
            gload_lds16(src + lane * 4,       &vbuf[s][0][0] + lane * 4);
            gload_lds16(src + 256 + lane * 4, &vbuf[s][8][0] + lane * 4);
        } else if (wave == 3) {
            const float* src = vf + base + (size_t)c * (CH * NS);
            gload_lds16(src + 512 + lane * 4, &vbuf[s][16][0] + lane * 4);
            gload_lds16(src + 768 + lane * 4, &vbuf[s][24][0] + lane * 4);
        } else if (wave == 4) {
            const unsigned short* src = qh + base + (size_t)c * (CH * NS);
            gload_lds16(src + lane * 8,       &qbuf[s][0][0] + lane * 8);
            gload_lds16(src + 512 + lane * 8, &qbuf[s][16][0] + lane * 8);
        } else if (wave == 5) {
            gload_lds4(decayb + dbase + (size_t)c * CH + lane,
                       &dbuf[s][0] + lane);    // tail lanes: junk, unused
        }
    };

    // Flush chunk cc's o values (obuf slot cc&3) to Sq: 32 rows x 64B.
    auto flush = [&](int cc) {
#pragma unroll
        for (int kk = 0; kk < 2; ++kk) {
            int row = kk * 16 + (lane >> 2);
            int seg = (lane & 3) * 8;
            uint4 dv = *(const uint4*)(&obuf[cc & 3][row][seg]);
            size_t go = ((size_t)(cc * CH + row) * BB + b) * KD + cbcol + seg;
            *(uint4*)(Sq + go) = dv;
        }
    };

    stage(0);
    stage(1);
    VMCNT(0);
    __builtin_amdgcn_s_barrier();

    float o_pend = 0.f;                        // un-reduced o of previous step

    for (int c = 0; c < NCHUNK; ++c) {
        if (c + 2 < NCHUNK) stage(c + 2);
        // Staging waves: outstanding = stage(c+1)[<=2] + stage(c+2)[<=2] = 4
        // -> VMCNT(4) drains stage(c). Compute-only waves: no global ops.
        if (wave < 6) { VMCNT(4); }
        __builtin_amdgcn_s_barrier();
        SB;
        if (wave == 6 && c >= 2) flush(c - 2);

        const int s = c & 3;
        const unsigned kb = kb0 + (unsigned)s * (CH * NS * 4);
        const unsigned qb = qb0 + (unsigned)s * (CH * NS * 2);
        const unsigned vb = vb0 + (unsigned)s * (CH * NS * 4);
        const unsigned db = db0 + (unsigned)s * 256;

        f32x2 kA[4], kB[4]; unsigned qA[4], qB[4]; float vA[4], vB[4];
        f32x4 dA, dB;

#define LDG(KK, QQ, VV, DV, g)                                          \
        KK[0] = dsr64f<((g) * 4 + 0) * 128>(kb);                        \
        KK[1] = dsr64f<((g) * 4 + 1) * 128>(kb);                        \
        KK[2] = dsr64f<((g) * 4 + 2) * 128>(kb);                        \
        KK[3] = dsr64f<((g) * 4 + 3) * 128>(kb);                        \
        QQ[0] = dsr32u<((g) * 4 + 0) * 64>(qb);                         \
        QQ[1] = dsr32u<((g) * 4 + 1) * 64>(qb);                         \
        QQ[2] = dsr32u<((g) * 4 + 2) * 64>(qb);                         \
        QQ[3] = dsr32u<((g) * 4 + 3) * 64>(qb);                         \
        VV[0] = dsr32f<((g) * 4 + 0) * 128>(vb);                        \
        VV[1] = dsr32f<((g) * 4 + 1) * 128>(vb);                        \
        VV[2] = dsr32f<((g) * 4 + 2) * 128>(vb);                        \
        VV[3] = dsr32f<((g) * 4 + 3) * 128>(vb);                        \
        DV    = dsr128<(g) * 16>(db);          /* broadcast: 4 decays */

#define CMP(KK, QQ, VV, DV, g)                                          \
        {                                                               \
            _Pragma("unroll")                                           \
            for (int p = 0; p < 4; ++p) {                               \
                float k0 = KK[p][0], k1 = KK[p][1];                     \
                float q0 = h2f((unsigned short)(QQ[p] & 0xffff));       \
                float q1 = h2f((unsigned short)(QQ[p] >> 16));          \
                float vj = VV[p];                                       \
                float d  = DV[p];                                       \
                float xr = fmaf(k1, s1, k0 * s0);                       \
                f32x2 rd = dpp_sum16x2(xr, o_pend);                     \
                if (ii == 0) {                                          \
                    if ((g) == 0 && p == 0) {                           \
                        if (c > 0) obuf[(c + 3) & 3][CH - 1][col] = f2h(rd[1]); \
                    } else {                                            \
                        obuf[s][(g) * 4 + p - 1][col] = f2h(rd[1]);     \
                    }                                                   \
                }                                                       \
                float delta = vj - rd[0];                               \
                float a0 = fmaf(d, s0, k0 * delta);                     \
                float a1 = fmaf(d, s1, k1 * delta);                     \
                s0 += tanh_fast(a0); s1 += tanh_fast(a1);               \
                o_pend = fmaf(q1, s1, q0 * s0);                         \
            }                                                           \
        }

        // 8-group pipeline: asm ds_reads can't be sunk; lgkmcnt(13) = wait
        // group done while next group's 13 DS ops stay in flight.
        LDG(kA, qA, vA, dA, 0);
        LDG(kB, qB, vB, dB, 1);
        LGKM(13); SB;
        CMP(kA, qA, vA, dA, 0);
        LDG(kA, qA, vA, dA, 2);
        LGKM(13); SB;
        CMP(kB, qB, vB, dB, 1);
        LDG(kB, qB, vB, dB, 3);
        LGKM(13); SB;
        CMP(kA, qA, vA, dA, 2);
        LDG(kA, qA, vA, dA, 4);
        LGKM(13); SB;
        CMP(kB, qB, vB, dB, 3);
        LDG(kB, qB, vB, dB, 5);
        LGKM(13); SB;
        CMP(kA, qA, vA, dA, 4);
        LDG(kA, qA, vA, dA, 6);
        LGKM(13); SB;
        CMP(kB, qB, vB, dB, 5);
        LDG(kB, qB, vB, dB, 7);
        LGKM(13); SB;
        CMP(kA, qA, vA, dA, 6);
        LGKM(0); SB;
        CMP(kB, qB, vB, dB, 7);
#undef LDG
#undef CMP
    }

    // Final pending o (t = T_LEN-1) -> last slot, then flush last two chunks.
    {
        float oo = dpp_sum16(o_pend);
        if (ii == 0) obuf[(NCHUNK - 1) & 3][CH - 1][col] = f2h(oo);
    }
    __builtin_amdgcn_s_barrier();
    if (wave == 6) { flush(NCHUNK - 2); flush(NCHUNK - 1); }

    float* so = Sout + (size_t)bh * NS * NS;
    so[(i0 + 0) * NS + col] = s0;
    so[(i0 + 1) * NS + col] = s1;
}

// ---------------------------------------------------------------------------
extern "C" void kernel_launch(void* const* d_in, const int* in_sizes, int n_in,
                              void* d_out, int out_size, void* d_ws, size_t ws_size,
                              hipStream_t stream) {
    const float* x       = (const float*)d_in[0];
    const float* S0      = (const float*)d_in[1];
    const float* Wq      = (const float*)d_in[2];
    const float* Wk      = (const float*)d_in[3];
    const float* Wv      = (const float*)d_in[4];
    const float* Wa      = (const float*)d_in[5];
    const float* A_log   = (const float*)d_in[6];
    const float* dt_bias = (const float*)d_in[7];
    const float* Wout    = (const float*)d_in[8];

    float* out  = (float*)d_out;
    float* Sout = out + (size_t)T_LEN * BB * DIM;

    // --- workspace layout (~171 MB peak) ---
    char* w = (char*)d_ws;
    auto alloc = [&](size_t bytes) {
        char* p = w; w += (bytes + 255) & ~(size_t)255; return p;
    };
    unsigned short* xh    = (unsigned short*)alloc((size_t)MROWS * DIM * 2); // 16.8 MB
    unsigned short* xl    = (unsigned short*)alloc((size_t)MROWS * DIM * 2); // 16.8 MB
    unsigned short* Wkh   = (unsigned short*)alloc((size_t)KD * DIM * 2);    // 3.67 MB
    unsigned short* Wkl   = (unsigned short*)alloc((size_t)KD * DIM * 2);    // 3.67 MB
    unsigned short* Wvh   = (unsigned short*)alloc((size_t)KD * DIM * 2);    // 3.67 MB
    unsigned short* Wvl   = (unsigned short*)alloc((size_t)KD * DIM * 2);    // 3.67 MB
    unsigned short* Wah   = (unsigned short*)alloc((size_t)HH * DIM * 2);    // 0.11 MB
    unsigned short* Wal   = (unsigned short*)alloc((size_t)HH * DIM * 2);    // 0.11 MB
    unsigned short* Wqh16 = (unsigned short*)alloc((size_t)KD * DIM * 2);    // 3.67 MB
    float* kf             = (float*)alloc((size_t)MROWS * KD * 4);           // 58.7 MB
    float* vf             = (float*)alloc((size_t)MROWS * KD * 4);           // 58.7 MB
    unsigned short* Woh   = (unsigned short*)alloc((size_t)DIM * KD * 2);    // 3.67 MB
    // Aliases: Sq (fp16) over xh/xl (x dead after kv-proj);
    //          x-fp16 over vf head (dead once v tiles of kv-proj run,
    //          which happens after q-gemm).
    unsigned short* Sq   = xh;
    unsigned short* xf16 = (unsigned short*)vf;

    // --- d_out head as scratch for q (fp16) + decay: dead before out GEMM ---
    unsigned short* qh  = (unsigned short*)d_out;                 // 29.36 MB
    float* decayb       = (float*)((char*)d_out + (size_t)MROWS * KD * 2); // 1.83 MB

    // 1) all casts in one launch
    {
        int items = MEGACAST_ITEMS;
        megacast_kernel<<<(items + 255) / 256, 256, 0, stream>>>(
            x, xh, xl, xf16, Wk, Wkh, Wkl, Wv, Wvh, Wvl,
            Wa, Wah, Wal, Wq, Wqh16, Wout, Woh);
    }
    // 2) q projection (fp16 MFMA, fused l2norm) -- must precede kv (xf16 alias)
    q_gemm_f16_kernel<<<dim3(14, 64), 256, 0, stream>>>(xf16, Wqh16, qh);
    // 3) fused k (norm) + decay + v projection
    kv_proj_kernel<<<dim3(29, 64), 256, 0, stream>>>(
        xh, xl, Wkh, Wkl, Wvh, Wvl, Wah, Wal, A_log, dt_bias, kf, vf, decayb);
    // 4) scan
    scan_kernel<<<BB * HH, 512, 0, stream>>>(kf, qh, vf, decayb, S0, Sq, Sout);
    // 5) output GEMM
    out_gemm_kernel<<<dim3(8, 64), 256, 0, stream>>>(Sq, Woh, out);
}

// Round 16
// 652.308 us; speedup vs baseline: 1.4330x; 1.0168x over previous
//
#include <hip/hip_runtime.h>

// ---------------------------------------------------------------------------
// E89 ResidualStateCell.
// Precision: k,v,decay (feed the recurrence) via split-bf16 (hi+lo) MFMA ->
// fp32; q,Sq,Wout (read-out only) via fp16 MFMA. Scan fp32 with fast tanh.
// Scan: 512 thr/bh (16 lanes/col x 2 elems), 4-deep LDS ring CH=32, counted
// vmcnt(4), inline-asm ds_read groups w/ lgkmcnt(13), delayed-o dual DPP
// reduction (builtin update_dpp: compiler inserts the required DPP hazard
// nops -- R15 lesson: raw v_add_f32_dpp asm races on the VALU->DPP hazard),
// LDS-buffered Sq flushed by wave 6.
// GEMMs: XCD-aware bijective block swizzle (T1) for L2 panel locality.
// Dispatch chain: megacast -> q-gemm -> fused k/decay/v proj -> scan ->
// out-gemm (5 launches).
// Layout: k,v,q transposed [B][H][T][NS], decay [B][H][T].
// Memory: ws ~171 MB. q fp16 + decay live in d_out head (dead before the
// final out-GEMM overwrites it). x-fp16 aliases vf head; Sq aliases xh/xl.
// ---------------------------------------------------------------------------

typedef __attribute__((ext_vector_type(8))) __bf16 bf16x8;
typedef __attribute__((ext_vector_type(8))) _Float16 f16x8;
typedef __attribute__((ext_vector_type(4))) float f32x4;
typedef __attribute__((ext_vector_type(2))) float f32x2;

#define T_LEN 2048
#define BB 4
#define HH 56
#define NS 32
#define DIM 1024
#define KD 1792            // H*NS
#define MROWS 8192         // T_LEN*BB
#define CH 32              // scan chunk (steps)
#define NCHUNK (T_LEN / CH)

#define VMCNT(N) asm volatile("s_waitcnt vmcnt(" #N ")" ::: "memory")
#define LGKM(N)  asm volatile("s_waitcnt lgkmcnt(" #N ")" ::: "memory")
#define SB       __builtin_amdgcn_sched_barrier(0)

__device__ __forceinline__ float bf2f(unsigned short u) {
    return __uint_as_float(((unsigned int)u) << 16);
}
__device__ __forceinline__ unsigned short f2bf(float f) {
    unsigned int u = __float_as_uint(f);
    u += 0x7fffu + ((u >> 16) & 1u);          // round-to-nearest-even
    return (unsigned short)(u >> 16);
}
__device__ __forceinline__ unsigned short f2h(float f) {
    union { _Float16 h; unsigned short u; } cv;
    cv.h = (_Float16)f;                       // RNE
    return cv.u;
}
__device__ __forceinline__ float h2f(unsigned short u) {
    union { unsigned short u; _Float16 h; } cv;
    cv.u = u;
    return (float)cv.h;
}

// tanh via v_exp_f32 (2^x): tanh(x) = 1 - 2/(1+2^(2*log2e*x))
__device__ __forceinline__ float tanh_fast(float x) {
    float e = __builtin_amdgcn_exp2f(x * 2.885390081777927f);
    float r = __builtin_amdgcn_rcpf(e + 1.0f);
    return fmaf(-2.0f, r, 1.0f);
}

// Sum across each aligned group of 16 lanes, pure-VALU DPP butterfly.
__device__ __forceinline__ float dpp_sum16(float x) {
    int t;
    t = __builtin_amdgcn_update_dpp(0, __float_as_int(x), 0xB1, 0xf, 0xf, true);
    x += __int_as_float(t);
    t = __builtin_amdgcn_update_dpp(0, __float_as_int(x), 0x4E, 0xf, 0xf, true);
    x += __int_as_float(t);
    t = __builtin_amdgcn_update_dpp(0, __float_as_int(x), 0x141, 0xf, 0xf, true);
    x += __int_as_float(t);
    t = __builtin_amdgcn_update_dpp(0, __float_as_int(x), 0x140, 0xf, 0xf, true);
    x += __int_as_float(t);
    return x;
}

// Dual 16-lane sum: two independent DPP trees, interleaved for ILP.
// Uses the builtin (compiler handles the VALU->DPP read hazard with nops).
__device__ __forceinline__ f32x2 dpp_sum16x2(float a, float b) {
    int ta, tb;
    ta = __builtin_amdgcn_update_dpp(0, __float_as_int(a), 0xB1, 0xf, 0xf, true);
    tb = __builtin_amdgcn_update_dpp(0, __float_as_int(b), 0xB1, 0xf, 0xf, true);
    a += __int_as_float(ta); b += __int_as_float(tb);
    ta = __builtin_amdgcn_update_dpp(0, __float_as_int(a), 0x4E, 0xf, 0xf, true);
    tb = __builtin_amdgcn_update_dpp(0, __float_as_int(b), 0x4E, 0xf, 0xf, true);
    a += __int_as_float(ta); b += __int_as_float(tb);
    ta = __builtin_amdgcn_update_dpp(0, __float_as_int(a), 0x141, 0xf, 0xf, true);
    tb = __builtin_amdgcn_update_dpp(0, __float_as_int(b), 0x141, 0xf, 0xf, true);
    a += __int_as_float(ta); b += __int_as_float(tb);
    ta = __builtin_amdgcn_update_dpp(0, __float_as_int(a), 0x140, 0xf, 0xf, true);
    tb = __builtin_amdgcn_update_dpp(0, __float_as_int(b), 0x140, 0xf, 0xf, true);
    a += __int_as_float(ta); b += __int_as_float(tb);
    return (f32x2){a, b};
}

__device__ __forceinline__ void gload_lds16(const void* g, void* l) {
    __builtin_amdgcn_global_load_lds(
        (const __attribute__((address_space(1))) unsigned int*)g,
        (__attribute__((address_space(3))) unsigned int*)l, 16, 0, 0);
}
__device__ __forceinline__ void gload_lds4(const void* g, void* l) {
    __builtin_amdgcn_global_load_lds(
        (const __attribute__((address_space(1))) unsigned int*)g,
        (__attribute__((address_space(3))) unsigned int*)l, 4, 0, 0);
}

// LDS byte offset of a generic pointer to __shared__ memory.
__device__ __forceinline__ unsigned lds_off(const void* p) {
    return (unsigned)(unsigned long long)
        (const __attribute__((address_space(3))) char*)p;
}

// Inline-asm LDS reads (opaque to the compiler: cannot be sunk/reordered).
template <int OFF>
__device__ __forceinline__ f32x4 dsr128(unsigned a) {
    f32x4 r;
    asm volatile("ds_read_b128 %0, %1 offset:%2" : "=v"(r) : "v"(a), "n"(OFF));
    return r;
}
template <int OFF>
__device__ __forceinline__ f32x2 dsr64f(unsigned a) {
    f32x2 r;
    asm volatile("ds_read_b64 %0, %1 offset:%2" : "=v"(r) : "v"(a), "n"(OFF));
    return r;
}
template <int OFF>
__device__ __forceinline__ unsigned dsr32u(unsigned a) {
    unsigned r;
    asm volatile("ds_read_b32 %0, %1 offset:%2" : "=v"(r) : "v"(a), "n"(OFF));
    return r;
}
template <int OFF>
__device__ __forceinline__ float dsr32f(unsigned a) {
    float r;
    asm volatile("ds_read_b32 %0, %1 offset:%2" : "=v"(r) : "v"(a), "n"(OFF));
    return r;
}

// XCD-aware bijective block swizzle (nwg divisible by 8).
__device__ __forceinline__ int xcd_swz(int bid, int nwg) {
    return (bid & 7) * (nwg >> 3) + (bid >> 3);
}

// ---------------------------------------------------------------------------
// Megacast: all input casts in one launch. Each thread handles 8 elements.
// ---------------------------------------------------------------------------
__device__ __forceinline__ void do_split8(const float* in, unsigned short* hi,
                                          unsigned short* lo, int i) {
    const float4* p = (const float4*)in + (size_t)i * 2;
    float4 a = p[0], b = p[1];
    float xs[8] = {a.x, a.y, a.z, a.w, b.x, b.y, b.z, b.w};
    unsigned int ho[4], lv[4];
#pragma unroll
    for (int c = 0; c < 4; ++c) {
        unsigned short h0 = f2bf(xs[2 * c]);
        unsigned short h1 = f2bf(xs[2 * c + 1]);
        unsigned short l0 = f2bf(xs[2 * c] - bf2f(h0));
        unsigned short l1 = f2bf(xs[2 * c + 1] - bf2f(h1));
        ho[c] = (unsigned int)h0 | ((unsigned int)h1 << 16);
        lv[c] = (unsigned int)l0 | ((unsigned int)l1 << 16);
    }
    ((uint4*)hi)[i] = (uint4){ho[0], ho[1], ho[2], ho[3]};
    ((uint4*)lo)[i] = (uint4){lv[0], lv[1], lv[2], lv[3]};
}
__device__ __forceinline__ void do_half8(const float* in, unsigned short* out, int i) {
    const float4* p = (const float4*)in + (size_t)i * 2;
    float4 a = p[0], b = p[1];
    uint4 o;
    o.x = (unsigned int)f2h(a.x) | ((unsigned int)f2h(a.y) << 16);
    o.y = (unsigned int)f2h(a.z) | ((unsigned int)f2h(a.w) << 16);
    o.z = (unsigned int)f2h(b.x) | ((unsigned int)f2h(b.y) << 16);
    o.w = (unsigned int)f2h(b.z) | ((unsigned int)f2h(b.w) << 16);
    ((uint4*)out)[i] = o;
}

__global__ void megacast_kernel(
    const float* __restrict__ x, unsigned short* __restrict__ xh,
    unsigned short* __restrict__ xl, unsigned short* __restrict__ xf16,
    const float* __restrict__ Wk, unsigned short* __restrict__ Wkh,
    unsigned short* __restrict__ Wkl,
    const float* __restrict__ Wv, unsigned short* __restrict__ Wvh,
    unsigned short* __restrict__ Wvl,
    const float* __restrict__ Wa, unsigned short* __restrict__ Wah,
    unsigned short* __restrict__ Wal,
    const float* __restrict__ Wq, unsigned short* __restrict__ Wqh16,
    const float* __restrict__ Wout, unsigned short* __restrict__ Woh) {
    int i = blockIdx.x * blockDim.x + threadIdx.x;
    const int N0 = MROWS * DIM / 8;            // x
    const int N1 = KD * DIM / 8;               // Wk/Wv/Wq/Wout
    const int N3 = HH * DIM / 8;               // Wa
    if (i < N0) {
        const float4* p = (const float4*)x + (size_t)i * 2;
        float4 a = p[0], b = p[1];
        float xs[8] = {a.x, a.y, a.z, a.w, b.x, b.y, b.z, b.w};
        unsigned int ho[4], lv[4], hv[4];
#pragma unroll
        for (int c = 0; c < 4; ++c) {
            unsigned short h0 = f2bf(xs[2 * c]);
            unsigned short h1 = f2bf(xs[2 * c + 1]);
            unsigned short l0 = f2bf(xs[2 * c] - bf2f(h0));
            unsigned short l1 = f2bf(xs[2 * c + 1] - bf2f(h1));
            ho[c] = (unsigned int)h0 | ((unsigned int)h1 << 16);
            lv[c] = (unsigned int)l0 | ((unsigned int)l1 << 16);
            hv[c] = (unsigned int)f2h(xs[2 * c]) |
                    ((unsigned int)f2h(xs[2 * c + 1]) << 16);
        }
        ((uint4*)xh)[i]   = (uint4){ho[0], ho[1], ho[2], ho[3]};
        ((uint4*)xl)[i]   = (uint4){lv[0], lv[1], lv[2], lv[3]};
        ((uint4*)xf16)[i] = (uint4){hv[0], hv[1], hv[2], hv[3]};
        return;
    }
    i -= N0;
    if (i < N1) { do_split8(Wk, Wkh, Wkl, i); return; }
    i -= N1;
    if (i < N1) { do_split8(Wv, Wvh, Wvl, i); return; }
    i -= N1;
    if (i < N3) { do_split8(Wa, Wah, Wal, i); return; }
    i -= N3;
    if (i < N1) { do_half8(Wq, Wqh16, i); return; }
    i -= N1;
    if (i < N1) { do_half8(Wout, Woh, i); }
}
#define MEGACAST_ITEMS (MROWS * DIM / 8 + 4 * (KD * DIM / 8) + HH * DIM / 8)

// ---------------------------------------------------------------------------
// Split MFMA GEMM core: Y[m,n] = sum_k A[m,k]*B[n,k], A=Ah+Al, B=Bh+Bl.
// 128x128 tile, BK=32, 256 threads = 4 waves (2x2), 16x16x32 bf16 MFMA x3.
// ---------------------------------------------------------------------------
__device__ __forceinline__ void gemm_split(
    const unsigned short* __restrict__ Ah, const unsigned short* __restrict__ Al,
    const unsigned short* __restrict__ Bh, const unsigned short* __restrict__ Bl,
    int m0, int n0, int K, int bmax,
    unsigned short* AsH, unsigned short* AsL,
    unsigned short* BsH, unsigned short* BsL,
    f32x4 (&acc)[4][4]) {
    const int tid  = threadIdx.x;
    const int lane = tid & 63;
    const int wave = tid >> 6;
    const int wm = wave >> 1, wn = wave & 1;
    const int lr = lane & 15, lkb = lane >> 4;

#pragma unroll
    for (int fr = 0; fr < 4; ++fr)
#pragma unroll
        for (int fc = 0; fc < 4; ++fc) acc[fr][fc] = (f32x4){0.f, 0.f, 0.f, 0.f};

    auto stage = [&](int kt) {
#pragma unroll
        for (int c = 0; c < 2; ++c) {
            int i = c * 256 + tid;
            int r = i >> 2, kk = (i & 3) << 3;
            size_t ao = (size_t)(m0 + r) * K + kt + kk;
            int br = n0 + r; if (br > bmax) br = bmax;
            size_t bo = (size_t)br * K + kt + kk;
            gload_lds16(Ah + ao, AsH + i * 8);
            gload_lds16(Al + ao, AsL + i * 8);
            gload_lds16(Bh + bo, BsH + i * 8);
            gload_lds16(Bl + bo, BsL + i * 8);
        }
    };

    stage(0);
    const int nk = K >> 5;
    for (int t = 0; t < nk; ++t) {
        __syncthreads();                       // drains vmcnt -> LDS tiles ready
        bf16x8 ah[4], al[4], bh[4], bl[4];
#pragma unroll
        for (int f = 0; f < 4; ++f) {
            int ai = (wm * 64 + f * 16 + lr) * 32 + lkb * 8;
            int bi = (wn * 64 + f * 16 + lr) * 32 + lkb * 8;
            ah[f] = *(const bf16x8*)(AsH + ai);
            al[f] = *(const bf16x8*)(AsL + ai);
            bh[f] = *(const bf16x8*)(BsH + bi);
            bl[f] = *(const bf16x8*)(BsL + bi);
        }
#pragma unroll
        for (int fr = 0; fr < 4; ++fr)
#pragma unroll
            for (int fc = 0; fc < 4; ++fc) {
                acc[fr][fc] = __builtin_amdgcn_mfma_f32_16x16x32_bf16(
                    ah[fr], bh[fc], acc[fr][fc], 0, 0, 0);
                acc[fr][fc] = __builtin_amdgcn_mfma_f32_16x16x32_bf16(
                    ah[fr], bl[fc], acc[fr][fc], 0, 0, 0);
                acc[fr][fc] = __builtin_amdgcn_mfma_f32_16x16x32_bf16(
                    al[fr], bh[fc], acc[fr][fc], 0, 0, 0);
            }
        __syncthreads();                       // all waves done reading LDS
        if (t + 1 < nk) stage((t + 1) << 5);
    }
}

// ---------------------------------------------------------------------------
// Fused k/decay/v projection.  Row m = t*BB + b.  XCD-swizzled grid.
// tile 0..13 : k  (silu + fused l2norm) -> fp32 kf  [B][H][T][NS]
// tile 14    : decay                    -> fp32 decayb [B][H][T]
// tile 15..28: v  (silu)                -> fp32 vf  [B][H][T][NS]
// ---------------------------------------------------------------------------
__global__ __launch_bounds__(256) void kv_proj_kernel(
    const unsigned short* __restrict__ xh, const unsigned short* __restrict__ xl,
    const unsigned short* __restrict__ Wkh, const unsigned short* __restrict__ Wkl,
    const unsigned short* __restrict__ Wvh, const unsigned short* __restrict__ Wvl,
    const unsigned short* __restrict__ Wah, const unsigned short* __restrict__ Wal,
    const float* __restrict__ A_log, const float* __restrict__ dt_bias,
    float* __restrict__ kf, float* __restrict__ vf,
    float* __restrict__ decayb) {
    __shared__ __align__(16) unsigned short AsH[128 * 32];
    __shared__ __align__(16) unsigned short AsL[128 * 32];
    __shared__ __align__(16) unsigned short BsH[128 * 32];
    __shared__ __align__(16) unsigned short BsL[128 * 32];

    int bid = blockIdx.y * gridDim.x + blockIdx.x;
    int swz = xcd_swz(bid, gridDim.x * gridDim.y);
    const int tile = swz % gridDim.x;          // 0..28
    const int ytile = swz / gridDim.x;         // 0..63

    int mode; const unsigned short *Bh, *Bl; int n0;
    if (tile < 14)       { mode = 0; Bh = Wkh; Bl = Wkl; n0 = tile * 128; }
    else if (tile == 14) { mode = 1; Bh = Wah; Bl = Wal; n0 = 0; }
    else                 { mode = 2; Bh = Wvh; Bl = Wvl; n0 = (tile - 15) * 128; }
    int m0 = ytile * 128;
    int bmax = (mode == 1) ? (HH - 1) : (KD - 1);

    f32x4 acc[4][4];
    gemm_split(xh, xl, Bh, Bl, m0, n0, DIM, bmax, AsH, AsL, BsH, BsL, acc);

    const int lane = threadIdx.x & 63, wave = threadIdx.x >> 6;
    const int wm = wave >> 1, wn = wave & 1, lr = lane & 15, lkb = lane >> 4;

    if (mode == 1) {
#pragma unroll
        for (int fr = 0; fr < 4; ++fr)
#pragma unroll
            for (int fc = 0; fc < 4; ++fc)
#pragma unroll
                for (int v = 0; v < 4; ++v) {
                    int m = m0 + wm * 64 + fr * 16 + lkb * 4 + v;
                    int n = n0 + wn * 64 + fc * 16 + lr;
                    int t = m >> 2, b = m & 3;
                    if (n < HH) {
                        float z = acc[fr][fc][v] + dt_bias[n];
                        float sp = (z > 20.f) ? z : log1pf(__expf(z));
                        decayb[((size_t)(b * HH + n)) * T_LEN + t] =
                            __expf(-__expf(A_log[n]) * sp);
                    }
                }
        return;
    }

    if (mode == 0) {
        // k: silu + fused l2norm over each head's 32 columns.
#pragma unroll
        for (int fr = 0; fr < 4; ++fr)
#pragma unroll
            for (int hc = 0; hc < 2; ++hc)
#pragma unroll
                for (int v = 0; v < 4; ++v) {
                    float yA = acc[fr][2 * hc][v];
                    float yB = acc[fr][2 * hc + 1][v];
                    float sA = yA / (1.f + __expf(-yA));
                    float sB = yB / (1.f + __expf(-yB));
                    float ss = fmaf(sA, sA, sB * sB);
                    ss = dpp_sum16(ss);            // sum over the head's 32 cols
                    float sc = 1.f / fmaxf(sqrtf(ss), 1e-12f);
                    int m = m0 + wm * 64 + fr * 16 + lkb * 4 + v;
                    int t = m >> 2, b = m & 3;
                    int h = ((n0 + wn * 64) >> 5) + hc;
                    size_t ro = (((size_t)(b * HH + h)) * T_LEN + t) * NS;
                    kf[ro + lr]      = sA * sc;
                    kf[ro + lr + 16] = sB * sc;
                }
    } else {
        // v: silu only
#pragma unroll
        for (int fr = 0; fr < 4; ++fr)
#pragma unroll
            for (int fc = 0; fc < 4; ++fc)
#pragma unroll
                for (int v = 0; v < 4; ++v) {
                    int m = m0 + wm * 64 + fr * 16 + lkb * 4 + v;
                    int n = n0 + wn * 64 + fc * 16 + lr;
                    int t = m >> 2, b = m & 3;
                    int h = n >> 5, i = n & 31;
                    float y = acc[fr][fc][v];
                    float s = y / (1.f + __expf(-y));
                    vf[(((size_t)(b * HH + h)) * T_LEN + t) * NS + i] = s;
                }
    }
}

// ---------------------------------------------------------------------------
// q projection, single fp16 MFMA (q is read-out-only): q = l2norm(silu(x@Wq^T)),
// fp16 store at [B][H][T][NS].  XCD-swizzled grid.
// ---------------------------------------------------------------------------
__global__ __launch_bounds__(256) void q_gemm_f16_kernel(
    const unsigned short* __restrict__ xf, const unsigned short* __restrict__ Wqf,
    unsigned short* __restrict__ dstH) {
    __shared__ __align__(16) unsigned short As[128 * 32];
    __shared__ __align__(16) unsigned short Bs[128 * 32];

    int bid = blockIdx.y * gridDim.x + blockIdx.x;
    int swz = xcd_swz(bid, gridDim.x * gridDim.y);
    int m0 = (swz / gridDim.x) * 128, n0 = (swz % gridDim.x) * 128;

    const int tid  = threadIdx.x;
    const int lane = tid & 63;
    const int wave = tid >> 6;
    const int wm = wave >> 1, wn = wave & 1;
    const int lr = lane & 15, lkb = lane >> 4;

    f32x4 acc[4][4];
#pragma unroll
    for (int fr = 0; fr < 4; ++fr)
#pragma unroll
        for (int fc = 0; fc < 4; ++fc) acc[fr][fc] = (f32x4){0.f, 0.f, 0.f, 0.f};

    auto stage = [&](int kt) {
#pragma unroll
        for (int c = 0; c < 2; ++c) {
            int i = c * 256 + tid;
            int r = i >> 2, kk = (i & 3) << 3;
            gload_lds16(xf + (size_t)(m0 + r) * DIM + kt + kk, As + i * 8);
            gload_lds16(Wqf + (size_t)(n0 + r) * DIM + kt + kk, Bs + i * 8);
        }
    };

    stage(0);
    const int nk = DIM >> 5;
    for (int t = 0; t < nk; ++t) {
        __syncthreads();
        f16x8 af[4], bf[4];
#pragma unroll
        for (int f = 0; f < 4; ++f) {
            af[f] = *(const f16x8*)(As + (wm * 64 + f * 16 + lr) * 32 + lkb * 8);
            bf[f] = *(const f16x8*)(Bs + (wn * 64 + f * 16 + lr) * 32 + lkb * 8);
        }
#pragma unroll
        for (int fr = 0; fr < 4; ++fr)
#pragma unroll
            for (int fc = 0; fc < 4; ++fc)
                acc[fr][fc] = __builtin_amdgcn_mfma_f32_16x16x32_f16(
                    af[fr], bf[fc], acc[fr][fc], 0, 0, 0);
        __syncthreads();
        if (t + 1 < nk) stage((t + 1) << 5);
    }

#pragma unroll
    for (int fr = 0; fr < 4; ++fr)
#pragma unroll
        for (int hc = 0; hc < 2; ++hc)
#pragma unroll
            for (int v = 0; v < 4; ++v) {
                float yA = acc[fr][2 * hc][v];
                float yB = acc[fr][2 * hc + 1][v];
                float sA = yA / (1.f + __expf(-yA));
                float sB = yB / (1.f + __expf(-yB));
                float ss = fmaf(sA, sA, sB * sB);
                ss = dpp_sum16(ss);
                float sc = 1.f / fmaxf(sqrtf(ss), 1e-12f);
                int m = m0 + wm * 64 + fr * 16 + lkb * 4 + v;
                int t = m >> 2, b = m & 3;
                int h = ((n0 + wn * 64) >> 5) + hc;
                size_t ro = (((size_t)(b * HH + h)) * T_LEN + t) * NS;
                dstH[ro + lr]      = f2h(sA * sc);
                dstH[ro + lr + 16] = f2h(sB * sc);
            }
}

// ---------------------------------------------------------------------------
// Output GEMM (fp16): out = Sq @ Wout^T, f32 store.  XCD-swizzled grid.
// ---------------------------------------------------------------------------
__global__ __launch_bounds__(256) void out_gemm_kernel(
    const unsigned short* __restrict__ Sq, const unsigned short* __restrict__ Wo,
    float* __restrict__ out) {
    __shared__ __align__(16) unsigned short As[128 * 32];
    __shared__ __align__(16) unsigned short Bs[128 * 32];

    int bid = blockIdx.y * gridDim.x + blockIdx.x;
    int swz = xcd_swz(bid, gridDim.x * gridDim.y);
    int m0 = (swz / gridDim.x) * 128, n0 = (swz % gridDim.x) * 128;

    const int tid  = threadIdx.x;
    const int lane = tid & 63;
    const int wave = tid >> 6;
    const int wm = wave >> 1, wn = wave & 1;
    const int lr = lane & 15, lkb = lane >> 4;

    f32x4 acc[4][4];
#pragma unroll
    for (int fr = 0; fr < 4; ++fr)
#pragma unroll
        for (int fc = 0; fc < 4; ++fc) acc[fr][fc] = (f32x4){0.f, 0.f, 0.f, 0.f};

    auto stage = [&](int kt) {
#pragma unroll
        for (int c = 0; c < 2; ++c) {
            int i = c * 256 + tid;
            int r = i >> 2, kk = (i & 3) << 3;
            gload_lds16(Sq + (size_t)(m0 + r) * KD + kt + kk, As + i * 8);
            gload_lds16(Wo + (size_t)(n0 + r) * KD + kt + kk, Bs + i * 8);
        }
    };

    stage(0);
    const int nk = KD >> 5;
    for (int t = 0; t < nk; ++t) {
        __syncthreads();
        f16x8 af[4], bf[4];
#pragma unroll
        for (int f = 0; f < 4; ++f) {
            af[f] = *(const f16x8*)(As + (wm * 64 + f * 16 + lr) * 32 + lkb * 8);
            bf[f] = *(const f16x8*)(Bs + (wn * 64 + f * 16 + lr) * 32 + lkb * 8);
        }
#pragma unroll
        for (int fr = 0; fr < 4; ++fr)
#pragma unroll
            for (int fc = 0; fc < 4; ++fc)
                acc[fr][fc] = __builtin_amdgcn_mfma_f32_16x16x32_f16(
                    af[fr], bf[fc], acc[fr][fc], 0, 0, 0);
        __syncthreads();
        if (t + 1 < nk) stage((t + 1) << 5);
    }

#pragma unroll
    for (int fr = 0; fr < 4; ++fr)
#pragma unroll
        for (int fc = 0; fc < 4; ++fc)
#pragma unroll
            for (int v = 0; v < 4; ++v) {
                int m = m0 + wm * 64 + fr * 16 + lkb * 4 + v;
                int n = n0 + wn * 64 + fc * 16 + lr;
                out[(size_t)m * DIM + n] = acc[fr][fc][v];
            }
}

// ---------------------------------------------------------------------------
// Sequential scan: 512 threads (8 waves) per (b,h); 16 lanes/col x 2 elems.
// CH=32 chunks, 4-deep LDS ring staged 2 ahead (waves 0-5, counted VMCNT(4));
// in-chunk 4-step groups via asm ds_read + lgkmcnt(13); delayed-o dual DPP
// reduction; Sq buffered in obuf, flushed chunk-wise by wave 6.
// ---------------------------------------------------------------------------
__global__ __launch_bounds__(512, 1) void scan_kernel(
    const float* __restrict__ kf, const unsigned short* __restrict__ qh,
    const float* __restrict__ vf, const float* __restrict__ decayb,
    const float* __restrict__ S0, unsigned short* __restrict__ Sq,
    float* __restrict__ Sout) {
    __shared__ __align__(16) float          kbuf[4][CH][NS];   // 16 KB
    __shared__ __align__(16) float          vbuf[4][CH][NS];   // 16 KB
    __shared__ __align__(16) unsigned short qbuf[4][CH][NS];   // 8 KB
    __shared__ __align__(16) float          dbuf[4][64];       // 1 KB
    __shared__ __align__(16) unsigned short obuf[4][CH][NS];   // 8 KB

    const int bh = blockIdx.x;                 // 0..223  (= b*HH + h)
    const int b = bh / HH, h = bh - b * HH;
    const int tid = threadIdx.x;
    const int lane = tid & 63, wave = tid >> 6;
    const int col = tid >> 4;                  // 0..31 (column j)
    const int ii  = tid & 15;                  // 0..15 (lane within column)
    const int i0  = ii * 2;                    // state elements i0, i0+1

    const float* Sp = S0 + (size_t)bh * NS * NS;
    float s0 = Sp[(i0 + 0) * NS + col];
    float s1 = Sp[(i0 + 1) * NS + col];

    const size_t base  = (size_t)bh * T_LEN * NS;
    const size_t dbase = (size_t)bh * T_LEN;
    const size_t cbcol = (size_t)h * NS;       // Sq column base

    // per-lane LDS base offsets (slot 0)
    const unsigned kb0 = lds_off(&kbuf[0][0][0]) + (unsigned)i0 * 4;
    const unsigned qb0 = lds_off(&qbuf[0][0][0]) + (unsigned)i0 * 2;
    const unsigned vb0 = lds_off(&vbuf[0][0][0]) + (unsigned)col * 4;
    const unsigned db0 = lds_off(&dbuf[0][0]);

    // Wave-specialized chunk staging (CH=32): waves 0-5, <=2 gload each.
    auto stage = [&](int c) {
        int s = c & 3;
        if (wave == 0) {
            const float* src = kf + base + (size_t)c * (CH * NS);
            gload_lds16(src + lane * 4,       &kbuf[s][0][0] + lane * 4);
            gload_lds16(src + 256 + lane * 4, &kbuf[s][8][0] + lane * 4);
        } else if (wave == 1) {
            const float* src = kf + base + (size_t)c * (CH * NS);
            gload_lds16(src + 512 + lane * 4, &kbuf[s][16][0] + lane * 4);
            gload_lds16(src + 768 + lane * 4, &kbuf[s][24][0] + lane * 4);
        } else if (wave == 2) {
            const float* src = vf + base + (size_t)c * (CH * NS);
            gload_lds16(src + lane * 4,       &vbuf[s][0][0] + lane * 4);
            gload_lds16(src + 256 + lane * 4, &vbuf[s][8][0] + lane * 4);
        } else if (wave == 3) {
            const float* src = vf + base + (size_t)c * (CH * NS);
            gload_lds16(src + 512 + lane * 4, &vbuf[s][16][0] + lane * 4);
            gload_lds16(src + 768 + lane * 4, &vbuf[s][24][0] + lane * 4);
        } else if (wave == 4) {
            const unsigned short* src = qh + base + (size_t)c * (CH * NS);
            gload_lds16(src + lane * 8,       &qbuf[s][0][0] + lane * 8);
            gload_lds16(src + 512 + lane * 8, &qbuf[s][16][0] + lane * 8);
        } else if (wave == 5) {
            gload_lds4(decayb + dbase + (size_t)c * CH + lane,
                       &dbuf[s][0] + lane);    // tail lanes: junk, unused
        }
    };

    // Flush chunk cc's o values (obuf slot cc&3) to Sq: 32 rows x 64B.
    auto flush = [&](int cc) {
#pragma unroll
        for (int kk = 0; kk < 2; ++kk) {
            int row = kk * 16 + (lane >> 2);
            int seg = (lane & 3) * 8;
            uint4 dv = *(const uint4*)(&obuf[cc & 3][row][seg]);
            size_t go = ((size_t)(cc * CH + row) * BB + b) * KD + cbcol + seg;
            *(uint4*)(Sq + go) = dv;
        }
    };

    stage(0);
    stage(1);
    VMCNT(0);
    __builtin_amdgcn_s_barrier();

    float o_pend = 0.f;                        // un-reduced o of previous step

    for (int c = 0; c < NCHUNK; ++c) {
        if (c + 2 < NCHUNK) stage(c + 2);
        // Staging waves: outstanding = stage(c+1)[<=2] + stage(c+2)[<=2] = 4
        // -> VMCNT(4) drains stage(c). Compute-only waves: no global ops.
        if (wave < 6) { VMCNT(4); }
        __builtin_amdgcn_s_barrier();
        SB;
        if (wave == 6 && c >= 2) flush(c - 2);

        const int s = c & 3;
        const unsigned kb = kb0 + (unsigned)s * (CH * NS * 4);
        const unsigned qb = qb0 + (unsigned)s * (CH * NS * 2);
        const unsigned vb = vb0 + (unsigned)s * (CH * NS * 4);
        const unsigned db = db0 + (unsigned)s * 256;

        f32x2 kA[4], kB[4]; unsigned qA[4], qB[4]; float vA[4], vB[4];
        f32x4 dA, dB;

#define LDG(KK, QQ, VV, DV, g)                                          \
        KK[0] = dsr64f<((g) * 4 + 0) * 128>(kb);                        \
        KK[1] = dsr64f<((g) * 4 + 1) * 128>(kb);                        \
        KK[2] = dsr64f<((g) * 4 + 2) * 128>(kb);                        \
        KK[3] = dsr64f<((g) * 4 + 3) * 128>(kb);                        \
        QQ[0] = dsr32u<((g) * 4 + 0) * 64>(qb);                         \
        QQ[1] = dsr32u<((g) * 4 + 1) * 64>(qb);                         \
        QQ[2] = dsr32u<((g) * 4 + 2) * 64>(qb);                         \
        QQ[3] = dsr32u<((g) * 4 + 3) * 64>(qb);                         \
        VV[0] = dsr32f<((g) * 4 + 0) * 128>(vb);                        \
        VV[1] = dsr32f<((g) * 4 + 1) * 128>(vb);                        \
        VV[2] = dsr32f<((g) * 4 + 2) * 128>(vb);                        \
        VV[3] = dsr32f<((g) * 4 + 3) * 128>(vb);                        \
        DV    = dsr128<(g) * 16>(db);          /* broadcast: 4 decays */

#define CMP(KK, QQ, VV, DV, g)                                          \
        {                                                               \
            _Pragma("unroll")                                           \
            for (int p = 0; p < 4; ++p) {                               \
                float k0 = KK[p][0], k1 = KK[p][1];                     \
                float q0 = h2f((unsigned short)(QQ[p] & 0xffff));       \
                float q1 = h2f((unsigned short)(QQ[p] >> 16));          \
                float vj = VV[p];                                       \
                float d  = DV[p];                                       \
                float xr = fmaf(k1, s1, k0 * s0);                       \
                f32x2 rd = dpp_sum16x2(xr, o_pend);                     \
                if (ii == 0) {                                          \
                    if ((g) == 0 && p == 0) {                           \
                        if (c > 0) obuf[(c + 3) & 3][CH - 1][col] = f2h(rd[1]); \
                    } else {                                            \
                        obuf[s][(g) * 4 + p - 1][col] = f2h(rd[1]);     \
                    }                                                   \
                }                                                       \
                float delta = vj - rd[0];                               \
                float a0 = fmaf(d, s0, k0 * delta);                     \
                float a1 = fmaf(d, s1, k1 * delta);                     \
                s0 += tanh_fast(a0); s1 += tanh_fast(a1);               \
                o_pend = fmaf(q1, s1, q0 * s0);                         \
            }                                                           \
        }

        // 8-group pipeline: asm ds_reads can't be sunk; lgkmcnt(13) = wait
        // group done while next group's 13 DS ops stay in flight.
        LDG(kA, qA, vA, dA, 0);
        LDG(kB, qB, vB, dB, 1);
        LGKM(13); SB;
        CMP(kA, qA, vA, dA, 0);
        LDG(kA, qA, vA, dA, 2);
        LGKM(13); SB;
        CMP(kB, qB, vB, dB, 1);
        LDG(kB, qB, vB, dB, 3);
        LGKM(13); SB;
        CMP(kA, qA, vA, dA, 2);
        LDG(kA, qA, vA, dA, 4);
        LGKM(13); SB;
        CMP(kB, qB, vB, dB, 3);
        LDG(kB, qB, vB, dB, 5);
        LGKM(13); SB;
        CMP(kA, qA, vA, dA, 4);
        LDG(kA, qA, vA, dA, 6);
        LGKM(13); SB;
        CMP(kB, qB, vB, dB, 5);
        LDG(kB, qB, vB, dB, 7);
        LGKM(13); SB;
        CMP(kA, qA, vA, dA, 6);
        LGKM(0); SB;
        CMP(kB, qB, vB, dB, 7);
#undef LDG
#undef CMP
    }

    // Final pending o (t = T_LEN-1) -> last slot, then flush last two chunks.
    {
        float oo = dpp_sum16(o_pend);
        if (ii == 0) obuf[(NCHUNK - 1) & 3][CH - 1][col] = f2h(oo);
    }
    __builtin_amdgcn_s_barrier();
    if (wave == 6) { flush(NCHUNK - 2); flush(NCHUNK - 1); }

    float* so = Sout + (size_t)bh * NS * NS;
    so[(i0 + 0) * NS + col] = s0;
    so[(i0 + 1) * NS + col] = s1;
}

// ---------------------------------------------------------------------------
extern "C" void kernel_launch(void* const* d_in, const int* in_sizes, int n_in,
                              void* d_out, int out_size, void* d_ws, size_t ws_size,
                              hipStream_t stream) {
    const float* x       = (const float*)d_in[0];
    const float* S0      = (const float*)d_in[1];
    const float* Wq      = (const float*)d_in[2];
    const float* Wk      = (const float*)d_in[3];
    const float* Wv      = (const float*)d_in[4];
    const float* Wa      = (const float*)d_in[5];
    const float* A_log   = (const float*)d_in[6];
    const float* dt_bias = (const float*)d_in[7];
    const float* Wout    = (const float*)d_in[8];

    float* out  = (float*)d_out;
    float* Sout = out + (size_t)T_LEN * BB * DIM;

    // --- workspace layout (~171 MB peak) ---
    char* w = (char*)d_ws;
    auto alloc = [&](size_t bytes) {
        char* p = w; w += (bytes + 255) & ~(size_t)255; return p;
    };
    unsigned short* xh    = (unsigned short*)alloc((size_t)MROWS * DIM * 2); // 16.8 MB
    unsigned short* xl    = (unsigned short*)alloc((size_t)MROWS * DIM * 2); // 16.8 MB
    unsigned short* Wkh   = (unsigned short*)alloc((size_t)KD * DIM * 2);    // 3.67 MB
    unsigned short* Wkl   = (unsigned short*)alloc((size_t)KD * DIM * 2);    // 3.67 MB
    unsigned short* Wvh   = (unsigned short*)alloc((size_t)KD * DIM * 2);    // 3.67 MB
    unsigned short* Wvl   = (unsigned short*)alloc((size_t)KD * DIM * 2);    // 3.67 MB
    unsigned short* Wah   = (unsigned short*)alloc((size_t)HH * DIM * 2);    // 0.11 MB
    unsigned short* Wal   = (unsigned short*)alloc((size_t)HH * DIM * 2);    // 0.11 MB
    unsigned short* Wqh16 = (unsigned short*)alloc((size_t)KD * DIM * 2);    // 3.67 MB
    float* kf             = (float*)alloc((size_t)MROWS * KD * 4);           // 58.7 MB
    float* vf             = (float*)alloc((size_t)MROWS * KD * 4);           // 58.7 MB
    unsigned short* Woh   = (unsigned short*)alloc((size_t)DIM * KD * 2);    // 3.67 MB
    // Aliases: Sq (fp16) over xh/xl (x dead after kv-proj);
    //          x-fp16 over vf head (dead once v tiles of kv-proj run,
    //          which happens after q-gemm).
    unsigned short* Sq   = xh;
    unsigned short* xf16 = (unsigned short*)vf;

    // --- d_out head as scratch for q (fp16) + decay: dead before out GEMM ---
    unsigned short* qh  = (unsigned short*)d_out;                 // 29.36 MB
    float* decayb       = (float*)((char*)d_out + (size_t)MROWS * KD * 2); // 1.83 MB

    // 1) all casts in one launch
    {
        int items = MEGACAST_ITEMS;
        megacast_kernel<<<(items + 255) / 256, 256, 0, stream>>>(
            x, xh, xl, xf16, Wk, Wkh, Wkl, Wv, Wvh, Wvl,
            Wa, Wah, Wal, Wq, Wqh16, Wout, Woh);
    }
    // 2) q projection (fp16 MFMA, fused l2norm) -- must precede kv (xf16 alias)
    q_gemm_f16_kernel<<<dim3(14, 64), 256, 0, stream>>>(xf16, Wqh16, qh);
    // 3) fused k (norm) + decay + v projection
    kv_proj_kernel<<<dim3(29, 64), 256, 0, stream>>>(
        xh, xl, Wkh, Wkl, Wvh, Wvl, Wah, Wal, A_log, dt_bias, kf, vf, decayb);
    // 4) scan
    scan_kernel<<<BB * HH, 512, 0, stream>>>(kf, qh, vf, decayb, S0, Sq, Sout);
    // 5) output GEMM
    out_gemm_kernel<<<dim3(8, 64), 256, 0, stream>>>(Sq, Woh, out);
}